// Round 8
// baseline (721.239 us; speedup 1.0000x reference)
//
#include <hip/hip_runtime.h>
#include <hip/hip_bf16.h>

typedef unsigned int uint32;
typedef unsigned short ushort16;

// float -> bf16 round-to-nearest-even
static __device__ __forceinline__ ushort16 f2bf(float f) {
    uint32 u = __float_as_uint(f);
    u += 0x7fffu + ((u >> 16) & 1u);
    return (ushort16)(u >> 16);
}
static __device__ __forceinline__ float blo(uint32 u) { return __uint_as_float(u << 16); }
static __device__ __forceinline__ float bhi(uint32 u) { return __uint_as_float(u & 0xffff0000u); }

// ============ CSR build over keys (dst<<3)|(src>>14): hist -> scan -> fill ============

__global__ void k_hist(const int* __restrict__ ei, int* __restrict__ cnt2, int E) {
    int e = blockIdx.x * blockDim.x + threadIdx.x;
    int stride = gridDim.x * blockDim.x;
    for (; e < E; e += stride) {
        int s = ei[e];
        int d = ei[E + e];
        atomicAdd(&cnt2[(d << 3) | (s >> 14)], 1);
    }
}

// exclusive scan over M elements (in-block part)
__global__ void k_scan1(const int* __restrict__ cnt2, int* __restrict__ rp2,
                        int* __restrict__ bsum, int M) {
    __shared__ int tmp[256];
    int i = blockIdx.x * 256 + threadIdx.x;
    int v = (i < M) ? cnt2[i] : 0;
    tmp[threadIdx.x] = v;
    __syncthreads();
    for (int off = 1; off < 256; off <<= 1) {
        int t = (threadIdx.x >= off) ? tmp[threadIdx.x - off] : 0;
        __syncthreads();
        tmp[threadIdx.x] += t;
        __syncthreads();
    }
    if (i < M) rp2[i] = tmp[threadIdx.x] - v;
    if (threadIdx.x == 255) bsum[blockIdx.x] = tmp[255];
}

// exclusive scan of up to 4096 block sums, single block of 1024
__global__ __launch_bounds__(1024) void k_scan2(int* bsum, int nb) {
    __shared__ int tot[1024];
    int t = threadIdx.x;
    int base = t * 4;
    int v0 = (base + 0 < nb) ? bsum[base + 0] : 0;
    int v1 = (base + 1 < nb) ? bsum[base + 1] : 0;
    int v2 = (base + 2 < nb) ? bsum[base + 2] : 0;
    int v3 = (base + 3 < nb) ? bsum[base + 3] : 0;
    int s = v0 + v1 + v2 + v3;
    tot[t] = s;
    __syncthreads();
    for (int off = 1; off < 1024; off <<= 1) {
        int u = (t >= off) ? tot[t - off] : 0;
        __syncthreads();
        tot[t] += u;
        __syncthreads();
    }
    int excl = tot[t] - s;
    if (base + 0 < nb) bsum[base + 0] = excl; excl += v0;
    if (base + 1 < nb) bsum[base + 1] = excl; excl += v1;
    if (base + 2 < nb) bsum[base + 2] = excl; excl += v2;
    if (base + 3 < nb) bsum[base + 3] = excl;
}

// finalize: cursor (d-major key order) + transposed pospd[p*N+d]
__global__ void k_scan3(const int* __restrict__ rp2, int* __restrict__ cursor2,
                        int* __restrict__ pospd, const int* __restrict__ bsum,
                        int M, int N) {
    int i = blockIdx.x * 256 + threadIdx.x;
    if (i < M) {
        int v = rp2[i] + bsum[blockIdx.x];
        cursor2[i] = v;
        pospd[(i & 7) * N + (i >> 3)] = v;
    }
}

__global__ void k_dinv2(const int* __restrict__ pospd, float* __restrict__ dinv,
                        int N, int E) {
    int d = blockIdx.x * 256 + threadIdx.x;
    if (d < N) {
        int beg = pospd[d];
        int end = (d + 1 < N) ? pospd[d + 1] : E;
        dinv[d] = rsqrtf((float)(end - beg + 1));   // +1 self loop
    }
}

// batched fill: 4 edges/thread, atomics pipelined; buckets sorted by (dst, src>>14)
__global__ __launch_bounds__(256) void k_fill(const int* __restrict__ ei,
                                              int* __restrict__ cursor2,
                                              int* __restrict__ ssrc, int E) {
    int t = blockIdx.x * 256 + threadIdx.x;
    int nt = gridDim.x * 256;
    int s[4], k[4], p[4];
#pragma unroll
    for (int i = 0; i < 4; ++i) {
        int e = t + i * nt;
        if (e < E) {
            s[i] = ei[e];
            int d = ei[E + e];
            k[i] = (d << 3) | (s[i] >> 14);
        }
    }
#pragma unroll
    for (int i = 0; i < 4; ++i) {
        int e = t + i * nt;
        if (e < E) p[i] = atomicAdd(&cursor2[k[i]], 1);
    }
#pragma unroll
    for (int i = 0; i < 4; ++i) {
        int e = t + i * nt;
        if (e < E) ssrc[p[i]] = s[i];
    }
}

// ============ embed GEMM: h = x @ We^T ([N,128] @ [128,64]^T) ============

__global__ __launch_bounds__(256) void k_embed(const float* __restrict__ x,
                                               const float* __restrict__ We,
                                               float* __restrict__ h, int N) {
    __shared__ float Ws[64 * 129];
    __shared__ float xs[32 * 128];
    int tid = threadIdx.x;

#pragma unroll
    for (int i = 0; i < 32; ++i) {
        int m = tid + i * 256;
        Ws[(m >> 7) * 129 + (m & 127)] = We[m];
    }
    int base = blockIdx.x * 32;
    const float4* x4 = (const float4*)(x + (size_t)base * 128);
#pragma unroll
    for (int i = 0; i < 4; ++i) {
        int m = tid + i * 256;
        ((float4*)xs)[m] = x4[m];
    }
    __syncthreads();

    int f = tid & 63, g = tid >> 6;
    float acc[8] = {0, 0, 0, 0, 0, 0, 0, 0};
#pragma unroll 4
    for (int k = 0; k < 128; k += 4) {
        float w0 = Ws[f * 129 + k + 0];
        float w1 = Ws[f * 129 + k + 1];
        float w2 = Ws[f * 129 + k + 2];
        float w3 = Ws[f * 129 + k + 3];
#pragma unroll
        for (int j = 0; j < 8; ++j) {
            const float4 xv = *(const float4*)&xs[(g * 8 + j) * 128 + k];
            acc[j] = fmaf(xv.x, w0, acc[j]);
            acc[j] = fmaf(xv.y, w1, acc[j]);
            acc[j] = fmaf(xv.z, w2, acc[j]);
            acc[j] = fmaf(xv.w, w3, acc[j]);
        }
    }
#pragma unroll
    for (int j = 0; j < 8; ++j) {
        int r = base + g * 8 + j;
        h[(size_t)r * 64 + f] = acc[j];
    }
}

// ============ GCN layer GEMM: hws = bf16((act(hin) @ Wg^T) * dinv) ============

__global__ __launch_bounds__(256) void k_gcn(const float* __restrict__ hin,
                                             const float* __restrict__ Wg,
                                             const float* __restrict__ bias_prev, int act,
                                             const float* __restrict__ dinv,
                                             ushort16* __restrict__ hwsb, int N) {
    __shared__ float Ws[64 * 65];
    __shared__ float xs[32 * 64];
    int tid = threadIdx.x;

#pragma unroll
    for (int i = 0; i < 16; ++i) {
        int m = tid + i * 256;
        Ws[(m >> 6) * 65 + (m & 63)] = Wg[m];
    }
    int base = blockIdx.x * 32;
    const float4* hin4 = (const float4*)(hin + (size_t)base * 64);
#pragma unroll
    for (int i = 0; i < 2; ++i) {
        int m = tid + i * 256;
        float4 v = hin4[m];
        if (act) {
            int kf = (m & 15) * 4;
            v.x = fmaxf(v.x + bias_prev[kf + 0], 0.f);
            v.y = fmaxf(v.y + bias_prev[kf + 1], 0.f);
            v.z = fmaxf(v.z + bias_prev[kf + 2], 0.f);
            v.w = fmaxf(v.w + bias_prev[kf + 3], 0.f);
        }
        ((float4*)xs)[m] = v;
    }
    __syncthreads();

    int f = tid & 63, g = tid >> 6;
    float acc[8] = {0, 0, 0, 0, 0, 0, 0, 0};
#pragma unroll 4
    for (int k = 0; k < 64; k += 4) {
        float w0 = Ws[f * 65 + k + 0];
        float w1 = Ws[f * 65 + k + 1];
        float w2 = Ws[f * 65 + k + 2];
        float w3 = Ws[f * 65 + k + 3];
#pragma unroll
        for (int j = 0; j < 8; ++j) {
            const float4 xv = *(const float4*)&xs[(g * 8 + j) * 64 + k];
            acc[j] = fmaf(xv.x, w0, acc[j]);
            acc[j] = fmaf(xv.y, w1, acc[j]);
            acc[j] = fmaf(xv.z, w2, acc[j]);
            acc[j] = fmaf(xv.w, w3, acc[j]);
        }
    }
#pragma unroll
    for (int j = 0; j < 8; ++j) {
        int r = base + g * 8 + j;
        hwsb[(size_t)r * 64 + f] = f2bf(acc[j] * dinv[r]);
    }
}

// ============ phase-swept CSR aggregate ============
// out[d] = dinv[d] * (hws[d] + sum_{e in row d} hws[src_e])
// Persistent-ish grid: 1250 blocks x 4 waves x 5 groups x 4 dsts = 100000.
// Each sub (16 lanes) owns one dst's full 128-B bf16 row accumulator.
// Outer loop over 8 src-phases: all resident waves gather from the same
// 2 MB hws bucket at a time -> per-XCD L2 locality. OOB lanes gather the
// zeroed sentinel row N.

__global__ __launch_bounds__(256) void k_agg(const int* __restrict__ pospd,
                                             const int* __restrict__ ssrc,
                                             const float* __restrict__ dinv,
                                             const uint2* __restrict__ hws2,
                                             float* __restrict__ out,
                                             int N, int E) {
    int wave = threadIdx.x >> 6;
    int lane = threadIdx.x & 63;
    int sub = lane >> 4;
    int q = lane & 15;
    int w = blockIdx.x * 4 + wave;
    int dbase = w * 20;          // 5 groups * 4 dsts

    float acc[5][4];
#pragma unroll
    for (int gi = 0; gi < 5; ++gi) {
        int d = dbase + gi * 4 + sub;
        float a0 = 0.f, a1 = 0.f, a2 = 0.f, a3 = 0.f;
        if (d < N) {
            uint2 v = hws2[((size_t)d << 4) + q];   // self loop
            a0 = blo(v.x); a1 = bhi(v.x); a2 = blo(v.y); a3 = bhi(v.y);
        }
        acc[gi][0] = a0; acc[gi][1] = a1; acc[gi][2] = a2; acc[gi][3] = a3;
    }

    for (int p = 0; p < 8; ++p) {
#pragma unroll
        for (int gi = 0; gi < 5; ++gi) {
            int d = dbase + gi * 4 + sub;
            int beg = 0, end = 0;
            if (d < N) {
                beg = pospd[p * N + d];
                end = (p < 7) ? pospd[(p + 1) * N + d]
                              : ((d + 1 < N) ? pospd[d + 1] : E);
            }
            for (int j = beg; __any(j < end); j += 2) {
                int i0 = (j < end) ? ssrc[j] : N;
                int i1 = (j + 1 < end) ? ssrc[j + 1] : N;
                uint2 v0 = hws2[((size_t)i0 << 4) + q];
                uint2 v1 = hws2[((size_t)i1 << 4) + q];
                acc[gi][0] += blo(v0.x) + blo(v1.x);
                acc[gi][1] += bhi(v0.x) + bhi(v1.x);
                acc[gi][2] += blo(v0.y) + blo(v1.y);
                acc[gi][3] += bhi(v0.y) + bhi(v1.y);
            }
        }
    }

#pragma unroll
    for (int gi = 0; gi < 5; ++gi) {
        int d = dbase + gi * 4 + sub;
        if (d < N) {
            float dd = dinv[d];
            ((float4*)out)[((size_t)d << 4) + q] =
                make_float4(dd * acc[gi][0], dd * acc[gi][1],
                            dd * acc[gi][2], dd * acc[gi][3]);
        }
    }
}

// ============ centroid squared norms ============

__global__ void k_c2(const float* __restrict__ C, float* __restrict__ c2) {
    int k = threadIdx.x;
    if (k < 100) {
        float s = 0.f;
        for (int d = 0; d < 64; ++d) { float v = C[k * 64 + d]; s = fmaf(v, v, s); }
        c2[k] = s;
    }
}

// ============ centroid distances + pooling: thread = node, quadratic form ============

__global__ __launch_bounds__(256) void k_cent(const float* __restrict__ hin,
                                              const float* __restrict__ b2,
                                              const float* __restrict__ C,
                                              const float* __restrict__ c2g,
                                              float* __restrict__ pooled, int N) {
    __shared__ float pooled_s[128];
    int tid = threadIdx.x;
    if (tid < 128) pooled_s[tid] = 0.f;
    __syncthreads();

    int n = blockIdx.x * 256 + tid;
    bool valid = n < N;

    float h[64];
    float h2 = 0.f;
    {
        const float4* h4 = (const float4*)(hin + ((size_t)(valid ? n : 0) << 6));
#pragma unroll
        for (int i = 0; i < 16; ++i) {
            float4 v = h4[i];
            v.x = fmaxf(v.x + b2[4 * i + 0], 0.f);
            v.y = fmaxf(v.y + b2[4 * i + 1], 0.f);
            v.z = fmaxf(v.z + b2[4 * i + 2], 0.f);
            v.w = fmaxf(v.w + b2[4 * i + 3], 0.f);
            h[4 * i + 0] = v.x; h[4 * i + 1] = v.y;
            h[4 * i + 2] = v.z; h[4 * i + 3] = v.w;
            h2 = fmaf(v.x, v.x, h2); h2 = fmaf(v.y, v.y, h2);
            h2 = fmaf(v.z, v.z, h2); h2 = fmaf(v.w, v.w, h2);
        }
    }

    for (int k = 0; k < 100; ++k) {
        const float* crow = C + k * 64;
        float acc = 0.f;
#pragma unroll
        for (int d = 0; d < 64; ++d) acc = fmaf(h[d], crow[d], acc);
        float d2 = fmaxf(h2 + c2g[k] - 2.f * acc, 0.f);
        float dist = valid ? sqrtf(d2 + 1e-12f) : 0.f;
#pragma unroll
        for (int off = 32; off > 0; off >>= 1) dist += __shfl_xor(dist, off);
        if ((tid & 63) == 0) atomicAdd(&pooled_s[k], dist);
    }
    __syncthreads();
    if (tid < 100) atomicAdd(&pooled[tid], pooled_s[tid]);
}

// ============ output head ============

__global__ void k_out(const float* __restrict__ pooled,
                      const float* __restrict__ Wout,
                      const float* __restrict__ bout,
                      float* __restrict__ out, float invN) {
    int t = threadIdx.x;
    if (t < 10) {
        float s = 0.f;
        for (int k = 0; k < 100; ++k) s += pooled[k] * Wout[t * 100 + k];
        out[t] = s * invN + bout[t];
    }
}

// ============ launcher ============

extern "C" void kernel_launch(void* const* d_in, const int* in_sizes, int n_in,
                              void* d_out, int out_size, void* d_ws, size_t ws_size,
                              hipStream_t stream) {
    const float* x    = (const float*)d_in[0];
    const int*   ei   = (const int*)d_in[1];
    const float* We   = (const float*)d_in[2];
    const float* Wg   = (const float*)d_in[3];
    const float* bg   = (const float*)d_in[4];
    const float* C    = (const float*)d_in[5];
    const float* Wout = (const float*)d_in[6];
    const float* bout = (const float*)d_in[7];
    float*       out  = (float*)d_out;

    const int N = in_sizes[0] / 128;    // 100000
    const int E = in_sizes[1] / 2;      // 1600000
    const int M = 8 * N;                // keys = (dst<<3)|(src>>14)
    const int NBM = (M + 255) / 256;    // 3125 scan blocks
    const int NBN = (N + 255) / 256;

    char* ws = (char*)d_ws;
    size_t off = 0;
    auto alloc = [&](size_t bytes) { void* p = ws + off; off += (bytes + 511) & ~(size_t)511; return p; };
    float*    dinv    = (float*)alloc((size_t)N * 4);
    int*      cnt2    = (int*)  alloc((size_t)M * 4);
    int*      rp2     = (int*)  alloc((size_t)M * 4);
    int*      cursor2 = (int*)  alloc((size_t)M * 4);
    int*      pospd   = (int*)  alloc((size_t)M * 4);
    int*      bsum    = (int*)  alloc((size_t)NBM * 4);
    int*      ssrc    = (int*)  alloc((size_t)E * 4);
    float*    hA      = (float*)alloc((size_t)N * 64 * 4);
    ushort16* hB      = (ushort16*)alloc((size_t)(N + 1) * 64 * 2);  // + sentinel row
    float*    c2      = (float*)alloc(512);
    float*    pooled  = (float*)alloc(512);

    hipMemsetAsync(cnt2, 0, (size_t)M * 4, stream);
    hipMemsetAsync(pooled, 0, 512, stream);
    hipMemsetAsync(hB + (size_t)N * 64, 0, 128, stream);   // sentinel row N = 0

    // CSR build over (dst, src-bucket) keys
    k_hist<<<4096, 256, 0, stream>>>(ei, cnt2, E);
    k_scan1<<<NBM, 256, 0, stream>>>(cnt2, rp2, bsum, M);
    k_scan2<<<1, 1024, 0, stream>>>(bsum, NBM);
    k_scan3<<<NBM, 256, 0, stream>>>(rp2, cursor2, pospd, bsum, M, N);
    k_dinv2<<<NBN, 256, 0, stream>>>(pospd, dinv, N, E);
    k_fill<<<(E + 1023) / 1024, 256, 0, stream>>>(ei, cursor2, ssrc, E);
    k_c2<<<1, 128, 0, stream>>>(C, c2);

    // embed
    k_embed<<<N / 32, 256, 0, stream>>>(x, We, hA, N);

    // 3 GCN layers: gemm (hA -> hB bf16, scaled by dinv), aggregate (hB -> hA fp32)
    for (int l = 0; l < 3; ++l) {
        const float* bias_prev = (l == 0) ? bg : (bg + (l - 1) * 64);
        int act = (l == 0) ? 0 : 1;
        k_gcn<<<N / 32, 256, 0, stream>>>(hA, Wg + (size_t)l * 64 * 64, bias_prev, act,
                                          dinv, hB, N);
        k_agg<<<(N + 79) / 80, 256, 0, stream>>>(pospd, ssrc, dinv,
                                                 (const uint2*)hB, hA, N, E);
    }

    // centroid distances + pooling (applies relu + b_gcn[2])
    k_cent<<<NBN, 256, 0, stream>>>(hA, bg + 2 * 64, C, c2, pooled, N);

    // head
    k_out<<<1, 64, 0, stream>>>(pooled, Wout, bout, out, 1.0f / (float)N);
}

// Round 9
// 682.239 us; speedup vs baseline: 1.0572x; 1.0572x over previous
//
#include <hip/hip_runtime.h>
#include <hip/hip_bf16.h>

typedef unsigned int uint32;
typedef unsigned short ushort16;

// float -> bf16 round-to-nearest-even
static __device__ __forceinline__ ushort16 f2bf(float f) {
    uint32 u = __float_as_uint(f);
    u += 0x7fffu + ((u >> 16) & 1u);
    return (ushort16)(u >> 16);
}
static __device__ __forceinline__ float blo(uint32 u) { return __uint_as_float(u << 16); }
static __device__ __forceinline__ float bhi(uint32 u) { return __uint_as_float(u & 0xffff0000u); }

// ============ CSR build: histogram -> scan -> fill (dst-only keys) ============

__global__ void k_hist(const int* __restrict__ dst, int* __restrict__ counts, int E) {
    int e = blockIdx.x * blockDim.x + threadIdx.x;
    int stride = gridDim.x * blockDim.x;
    for (; e < E; e += stride) atomicAdd(&counts[dst[e]], 1);
}

__global__ void k_dinv(const int* __restrict__ counts, float* __restrict__ dinv, int N) {
    int i = blockIdx.x * blockDim.x + threadIdx.x;
    if (i < N) dinv[i] = rsqrtf((float)(counts[i] + 1));   // +1 self loop
}

__global__ void k_scan1(const int* __restrict__ counts, int* __restrict__ rowptr,
                        int* __restrict__ bsum, int N) {
    __shared__ int tmp[256];
    int i = blockIdx.x * 256 + threadIdx.x;
    int v = (i < N) ? counts[i] : 0;
    tmp[threadIdx.x] = v;
    __syncthreads();
    for (int off = 1; off < 256; off <<= 1) {
        int t = (threadIdx.x >= off) ? tmp[threadIdx.x - off] : 0;
        __syncthreads();
        tmp[threadIdx.x] += t;
        __syncthreads();
    }
    if (i < N) rowptr[i] = tmp[threadIdx.x] - v;
    if (threadIdx.x == 255) bsum[blockIdx.x] = tmp[255];
}

__global__ void k_scan2(int* bsum, int nb) {
    __shared__ int tmp[512];
    int t = threadIdx.x;
    int v = (t < nb) ? bsum[t] : 0;
    tmp[t] = v;
    __syncthreads();
    for (int off = 1; off < 512; off <<= 1) {
        int u = (t >= off) ? tmp[t - off] : 0;
        __syncthreads();
        tmp[t] += u;
        __syncthreads();
    }
    if (t < nb) bsum[t] = tmp[t] - v;
}

__global__ void k_scan3(int* __restrict__ rowptr, int* __restrict__ cursor,
                        const int* __restrict__ bsum, int N) {
    int i = blockIdx.x * 256 + threadIdx.x;
    if (i < N) {
        int v = rowptr[i] + bsum[blockIdx.x];
        rowptr[i] = v;
        cursor[i] = v;
    }
}

// batched fill: 4 edges/thread (1563 blocks, measured sweet spot), atomics pipelined
__global__ __launch_bounds__(256) void k_fill(const int* __restrict__ ei,
                                              int* __restrict__ cursor,
                                              int* __restrict__ ssrc, int E) {
    int t = blockIdx.x * 256 + threadIdx.x;
    int nt = gridDim.x * 256;
    int s[4], d[4], p[4];
#pragma unroll
    for (int i = 0; i < 4; ++i) {
        int e = t + i * nt;
        if (e < E) { s[i] = ei[e]; d[i] = ei[E + e]; }
    }
#pragma unroll
    for (int i = 0; i < 4; ++i) {
        int e = t + i * nt;
        if (e < E) p[i] = atomicAdd(&cursor[d[i]], 1);
    }
#pragma unroll
    for (int i = 0; i < 4; ++i) {
        int e = t + i * nt;
        if (e < E) ssrc[p[i]] = s[i];
    }
}

// ============ embed GEMM: h = x @ We^T ([N,128] @ [128,64]^T) ============

__global__ __launch_bounds__(256) void k_embed(const float* __restrict__ x,
                                               const float* __restrict__ We,
                                               float* __restrict__ h, int N) {
    __shared__ float Ws[64 * 129];
    __shared__ float xs[32 * 128];
    int tid = threadIdx.x;

#pragma unroll
    for (int i = 0; i < 32; ++i) {
        int m = tid + i * 256;
        Ws[(m >> 7) * 129 + (m & 127)] = We[m];
    }
    int base = blockIdx.x * 32;
    const float4* x4 = (const float4*)(x + (size_t)base * 128);
#pragma unroll
    for (int i = 0; i < 4; ++i) {
        int m = tid + i * 256;
        ((float4*)xs)[m] = x4[m];
    }
    __syncthreads();

    int f = tid & 63, g = tid >> 6;
    float acc[8] = {0, 0, 0, 0, 0, 0, 0, 0};
#pragma unroll 4
    for (int k = 0; k < 128; k += 4) {
        float w0 = Ws[f * 129 + k + 0];
        float w1 = Ws[f * 129 + k + 1];
        float w2 = Ws[f * 129 + k + 2];
        float w3 = Ws[f * 129 + k + 3];
#pragma unroll
        for (int j = 0; j < 8; ++j) {
            const float4 xv = *(const float4*)&xs[(g * 8 + j) * 128 + k];
            acc[j] = fmaf(xv.x, w0, acc[j]);
            acc[j] = fmaf(xv.y, w1, acc[j]);
            acc[j] = fmaf(xv.z, w2, acc[j]);
            acc[j] = fmaf(xv.w, w3, acc[j]);
        }
    }
#pragma unroll
    for (int j = 0; j < 8; ++j) {
        int r = base + g * 8 + j;
        h[(size_t)r * 64 + f] = acc[j];
    }
}

// ============ GCN layer GEMM: split bf16 tables tabA (cols 0-31), tabB (32-63) ====

__global__ __launch_bounds__(256) void k_gcn(const float* __restrict__ hin,
                                             const float* __restrict__ Wg,
                                             const float* __restrict__ bias_prev, int act,
                                             const float* __restrict__ dinv,
                                             ushort16* __restrict__ tabA,
                                             ushort16* __restrict__ tabB, int N) {
    __shared__ float Ws[64 * 65];
    __shared__ float xs[32 * 64];
    int tid = threadIdx.x;

#pragma unroll
    for (int i = 0; i < 16; ++i) {
        int m = tid + i * 256;
        Ws[(m >> 6) * 65 + (m & 63)] = Wg[m];
    }
    int base = blockIdx.x * 32;
    const float4* hin4 = (const float4*)(hin + (size_t)base * 64);
#pragma unroll
    for (int i = 0; i < 2; ++i) {
        int m = tid + i * 256;
        float4 v = hin4[m];
        if (act) {
            int kf = (m & 15) * 4;
            v.x = fmaxf(v.x + bias_prev[kf + 0], 0.f);
            v.y = fmaxf(v.y + bias_prev[kf + 1], 0.f);
            v.z = fmaxf(v.z + bias_prev[kf + 2], 0.f);
            v.w = fmaxf(v.w + bias_prev[kf + 3], 0.f);
        }
        ((float4*)xs)[m] = v;
    }
    __syncthreads();

    int f = tid & 63, g = tid >> 6;
    float acc[8] = {0, 0, 0, 0, 0, 0, 0, 0};
#pragma unroll 4
    for (int k = 0; k < 64; k += 4) {
        float w0 = Ws[f * 65 + k + 0];
        float w1 = Ws[f * 65 + k + 1];
        float w2 = Ws[f * 65 + k + 2];
        float w3 = Ws[f * 65 + k + 3];
#pragma unroll
        for (int j = 0; j < 8; ++j) {
            const float4 xv = *(const float4*)&xs[(g * 8 + j) * 64 + k];
            acc[j] = fmaf(xv.x, w0, acc[j]);
            acc[j] = fmaf(xv.y, w1, acc[j]);
            acc[j] = fmaf(xv.z, w2, acc[j]);
            acc[j] = fmaf(xv.w, w3, acc[j]);
        }
    }
    ushort16* tab = (f < 32) ? tabA : tabB;
    int fc = f & 31;
#pragma unroll
    for (int j = 0; j < 8; ++j) {
        int r = base + g * 8 + j;
        tab[(size_t)r * 32 + fc] = f2bf(acc[j] * dinv[r]);
    }
}

// ============ feature-split CSR gather-aggregate (one half per launch) ============
// out[d][half] = dinv[d] * (tab[d] + sum_{e in row d} tab[src_e])
// One wave per dst. sub = lane>>3 picks 1 of 8 rows per gather instruction,
// q = lane&7 picks the uint2 (4 bf16) within the 64-B row. Edge indices come
// from wave-uniform scalar loads; row-select via 3-deep cndmask tree.

__global__ __launch_bounds__(256) void k_agg(const int* __restrict__ rowptr,
                                             const int* __restrict__ counts,
                                             const int* __restrict__ ssrc,
                                             const float* __restrict__ dinv,
                                             const uint2* __restrict__ tab,
                                             float* __restrict__ out,
                                             int halfOff, int N) {
    int lane = threadIdx.x & 63;
    int d = blockIdx.x * 4 + (threadIdx.x >> 6);
    if (d >= N) return;
    int q = lane & 7;
    int sub = lane >> 3;
    bool b1 = (sub & 1) != 0, b2 = (sub & 2) != 0, b4 = (sub & 4) != 0;

    float a0 = 0.f, a1 = 0.f, a2 = 0.f, a3 = 0.f;
    if (sub == 0) {   // self loop counted once
        uint2 v = tab[(size_t)d * 8 + q];
        a0 = blo(v.x); a1 = bhi(v.x); a2 = blo(v.y); a3 = bhi(v.y);
    }

    int beg = __builtin_amdgcn_readfirstlane(rowptr[d]);
    int cnt = __builtin_amdgcn_readfirstlane(counts[d]);
    const int* srow = ssrc + beg;

#define SEL8(e0,e1,e2,e3,e4,e5,e6,e7) \
    (b4 ? (b2 ? (b1 ? e7 : e6) : (b1 ? e5 : e4)) \
        : (b2 ? (b1 ? e3 : e2) : (b1 ? e1 : e0)))

    int j = 0;
    for (; j + 16 <= cnt; j += 16) {
        int e0 = srow[j + 0],  e1 = srow[j + 1],  e2 = srow[j + 2],  e3 = srow[j + 3];
        int e4 = srow[j + 4],  e5 = srow[j + 5],  e6 = srow[j + 6],  e7 = srow[j + 7];
        int e8 = srow[j + 8],  e9 = srow[j + 9],  ea = srow[j + 10], eb = srow[j + 11];
        int ec = srow[j + 12], ed = srow[j + 13], ee = srow[j + 14], ef = srow[j + 15];
        int t0 = SEL8(e0, e1, e2, e3, e4, e5, e6, e7);
        int t1 = SEL8(e8, e9, ea, eb, ec, ed, ee, ef);
        uint2 v0 = tab[(size_t)t0 * 8 + q];
        uint2 v1 = tab[(size_t)t1 * 8 + q];
        a0 += blo(v0.x) + blo(v1.x);
        a1 += bhi(v0.x) + bhi(v1.x);
        a2 += blo(v0.y) + blo(v1.y);
        a3 += bhi(v0.y) + bhi(v1.y);
    }
    int rem = cnt - j;   // 0..15, wave-uniform
    if (rem) {
        // ssrc is padded by 16 ints, so reading 16 ahead is safe; OOB -> sentinel N
        int e0 = srow[j + 0],  e1 = srow[j + 1],  e2 = srow[j + 2],  e3 = srow[j + 3];
        int e4 = srow[j + 4],  e5 = srow[j + 5],  e6 = srow[j + 6],  e7 = srow[j + 7];
        int t0 = SEL8(e0, e1, e2, e3, e4, e5, e6, e7);
        t0 = (sub < rem) ? t0 : N;
        uint2 v0 = tab[(size_t)t0 * 8 + q];
        a0 += blo(v0.x); a1 += bhi(v0.x); a2 += blo(v0.y); a3 += bhi(v0.y);
        if (rem > 8) {
            int e8 = srow[j + 8],  e9 = srow[j + 9],  ea = srow[j + 10], eb = srow[j + 11];
            int ec = srow[j + 12], ed = srow[j + 13], ee = srow[j + 14], ef = srow[j + 15];
            int t1 = SEL8(e8, e9, ea, eb, ec, ed, ee, ef);
            t1 = (sub + 8 < rem) ? t1 : N;
            uint2 v1 = tab[(size_t)t1 * 8 + q];
            a0 += blo(v1.x); a1 += bhi(v1.x); a2 += blo(v1.y); a3 += bhi(v1.y);
        }
    }
#undef SEL8

    // reduce across the 8 subs (lanes 8 apart hold the same q)
    a0 += __shfl_xor(a0, 8);  a1 += __shfl_xor(a1, 8);
    a2 += __shfl_xor(a2, 8);  a3 += __shfl_xor(a3, 8);
    a0 += __shfl_xor(a0, 16); a1 += __shfl_xor(a1, 16);
    a2 += __shfl_xor(a2, 16); a3 += __shfl_xor(a3, 16);
    a0 += __shfl_xor(a0, 32); a1 += __shfl_xor(a1, 32);
    a2 += __shfl_xor(a2, 32); a3 += __shfl_xor(a3, 32);

    if (sub == 0) {
        float dd = dinv[d];
        ((float4*)out)[(size_t)d * 16 + halfOff + q] =
            make_float4(dd * a0, dd * a1, dd * a2, dd * a3);
    }
}

// ============ centroid squared norms ============

__global__ void k_c2(const float* __restrict__ C, float* __restrict__ c2) {
    int k = threadIdx.x;
    if (k < 100) {
        float s = 0.f;
        for (int d = 0; d < 64; ++d) { float v = C[k * 64 + d]; s = fmaf(v, v, s); }
        c2[k] = s;
    }
}

// ============ centroid distances + pooling: thread = node, quadratic form ============

__global__ __launch_bounds__(256) void k_cent(const float* __restrict__ hin,
                                              const float* __restrict__ b2,
                                              const float* __restrict__ C,
                                              const float* __restrict__ c2g,
                                              float* __restrict__ pooled, int N) {
    __shared__ float pooled_s[128];
    int tid = threadIdx.x;
    if (tid < 128) pooled_s[tid] = 0.f;
    __syncthreads();

    int n = blockIdx.x * 256 + tid;
    bool valid = n < N;

    float h[64];
    float h2 = 0.f;
    {
        const float4* h4 = (const float4*)(hin + ((size_t)(valid ? n : 0) << 6));
#pragma unroll
        for (int i = 0; i < 16; ++i) {
            float4 v = h4[i];
            v.x = fmaxf(v.x + b2[4 * i + 0], 0.f);
            v.y = fmaxf(v.y + b2[4 * i + 1], 0.f);
            v.z = fmaxf(v.z + b2[4 * i + 2], 0.f);
            v.w = fmaxf(v.w + b2[4 * i + 3], 0.f);
            h[4 * i + 0] = v.x; h[4 * i + 1] = v.y;
            h[4 * i + 2] = v.z; h[4 * i + 3] = v.w;
            h2 = fmaf(v.x, v.x, h2); h2 = fmaf(v.y, v.y, h2);
            h2 = fmaf(v.z, v.z, h2); h2 = fmaf(v.w, v.w, h2);
        }
    }

    for (int k = 0; k < 100; ++k) {
        const float* crow = C + k * 64;
        float acc = 0.f;
#pragma unroll
        for (int d = 0; d < 64; ++d) acc = fmaf(h[d], crow[d], acc);
        float d2 = fmaxf(h2 + c2g[k] - 2.f * acc, 0.f);
        float dist = valid ? sqrtf(d2 + 1e-12f) : 0.f;
#pragma unroll
        for (int off = 32; off > 0; off >>= 1) dist += __shfl_xor(dist, off);
        if ((tid & 63) == 0) atomicAdd(&pooled_s[k], dist);
    }
    __syncthreads();
    if (tid < 100) atomicAdd(&pooled[tid], pooled_s[tid]);
}

// ============ output head ============

__global__ void k_out(const float* __restrict__ pooled,
                      const float* __restrict__ Wout,
                      const float* __restrict__ bout,
                      float* __restrict__ out, float invN) {
    int t = threadIdx.x;
    if (t < 10) {
        float s = 0.f;
        for (int k = 0; k < 100; ++k) s += pooled[k] * Wout[t * 100 + k];
        out[t] = s * invN + bout[t];
    }
}

// ============ launcher ============

extern "C" void kernel_launch(void* const* d_in, const int* in_sizes, int n_in,
                              void* d_out, int out_size, void* d_ws, size_t ws_size,
                              hipStream_t stream) {
    const float* x    = (const float*)d_in[0];
    const int*   ei   = (const int*)d_in[1];
    const float* We   = (const float*)d_in[2];
    const float* Wg   = (const float*)d_in[3];
    const float* bg   = (const float*)d_in[4];
    const float* C    = (const float*)d_in[5];
    const float* Wout = (const float*)d_in[6];
    const float* bout = (const float*)d_in[7];
    float*       out  = (float*)d_out;

    const int N = in_sizes[0] / 128;    // 100000
    const int E = in_sizes[1] / 2;      // 1600000
    const int NB = (N + 255) / 256;     // scan blocks (391)

    char* ws = (char*)d_ws;
    size_t off = 0;
    auto alloc = [&](size_t bytes) { void* p = ws + off; off += (bytes + 511) & ~(size_t)511; return p; };
    float*    dinv   = (float*)alloc((size_t)N * 4);
    int*      counts = (int*)  alloc((size_t)N * 4);
    int*      cursor = (int*)  alloc((size_t)N * 4);
    int*      rowptr = (int*)  alloc((size_t)N * 4);
    int*      bsum   = (int*)  alloc((size_t)NB * 4);
    int*      ssrc   = (int*)  alloc((size_t)(E + 16) * 4);      // +16 pad for agg reads
    float*    hA     = (float*)alloc((size_t)N * 64 * 4);
    ushort16* tabA   = (ushort16*)alloc((size_t)(N + 1) * 32 * 2);  // + sentinel row
    ushort16* tabB   = (ushort16*)alloc((size_t)(N + 1) * 32 * 2);  // + sentinel row
    float*    c2     = (float*)alloc(512);
    float*    pooled = (float*)alloc(512);

    hipMemsetAsync(counts, 0, (size_t)N * 4, stream);
    hipMemsetAsync(pooled, 0, 512, stream);
    hipMemsetAsync(tabA + (size_t)N * 32, 0, 64, stream);   // sentinel rows = 0
    hipMemsetAsync(tabB + (size_t)N * 32, 0, 64, stream);

    // CSR build (dst-only)
    k_hist<<<4096, 256, 0, stream>>>(ei + E, counts, E);
    k_dinv<<<NB, 256, 0, stream>>>(counts, dinv, N);
    k_scan1<<<NB, 256, 0, stream>>>(counts, rowptr, bsum, N);
    k_scan2<<<1, 512, 0, stream>>>(bsum, NB);
    k_scan3<<<NB, 256, 0, stream>>>(rowptr, cursor, bsum, N);
    k_fill<<<(E + 1023) / 1024, 256, 0, stream>>>(ei, cursor, ssrc, E);
    k_c2<<<1, 128, 0, stream>>>(C, c2);

    // embed
    k_embed<<<N / 32, 256, 0, stream>>>(x, We, hA, N);

    // 3 GCN layers: gemm (hA -> tabA/tabB bf16, scaled by dinv), agg halves (-> hA)
    for (int l = 0; l < 3; ++l) {
        const float* bias_prev = (l == 0) ? bg : (bg + (l - 1) * 64);
        int act = (l == 0) ? 0 : 1;
        k_gcn<<<N / 32, 256, 0, stream>>>(hA, Wg + (size_t)l * 64 * 64, bias_prev, act,
                                          dinv, tabA, tabB, N);
        k_agg<<<(N + 3) / 4, 256, 0, stream>>>(rowptr, counts, ssrc, dinv,
                                               (const uint2*)tabA, hA, 0, N);
        k_agg<<<(N + 3) / 4, 256, 0, stream>>>(rowptr, counts, ssrc, dinv,
                                               (const uint2*)tabB, hA, 8, N);
    }

    // centroid distances + pooling (applies relu + b_gcn[2])
    k_cent<<<NB, 256, 0, stream>>>(hA, bg + 2 * 64, C, c2, pooled, N);

    // head
    k_out<<<1, 64, 0, stream>>>(pooled, Wout, bout, out, 1.0f / (float)N);
}

// Round 10
// 575.094 us; speedup vs baseline: 1.2541x; 1.1863x over previous
//
#include <hip/hip_runtime.h>
#include <hip/hip_bf16.h>

typedef unsigned int uint32;
typedef float floatx2 __attribute__((ext_vector_type(2)));

// ============ CSR build: histogram -> scan(+dinv) -> fill (dst keys) ============

__global__ void k_hist(const int* __restrict__ dst, int* __restrict__ counts, int E) {
    int e = blockIdx.x * blockDim.x + threadIdx.x;
    int stride = gridDim.x * blockDim.x;
    for (; e < E; e += stride) atomicAdd(&counts[dst[e]], 1);
}

// block-local exclusive scan; also emits dinv = rsqrt(count+1)
__global__ void k_scan1(const int* __restrict__ counts, int* __restrict__ rowptr,
                        int* __restrict__ bsum, float* __restrict__ dinv, int N) {
    __shared__ int tmp[256];
    int i = blockIdx.x * 256 + threadIdx.x;
    int v = (i < N) ? counts[i] : 0;
    if (i < N) dinv[i] = rsqrtf((float)(v + 1));   // +1 self loop
    tmp[threadIdx.x] = v;
    __syncthreads();
    for (int off = 1; off < 256; off <<= 1) {
        int t = (threadIdx.x >= off) ? tmp[threadIdx.x - off] : 0;
        __syncthreads();
        tmp[threadIdx.x] += t;
        __syncthreads();
    }
    if (i < N) rowptr[i] = tmp[threadIdx.x] - v;
    if (threadIdx.x == 255) bsum[blockIdx.x] = tmp[255];
}

__global__ void k_scan2(int* bsum, int nb) {
    __shared__ int tmp[512];
    int t = threadIdx.x;
    int v = (t < nb) ? bsum[t] : 0;
    tmp[t] = v;
    __syncthreads();
    for (int off = 1; off < 512; off <<= 1) {
        int u = (t >= off) ? tmp[t - off] : 0;
        __syncthreads();
        tmp[t] += u;
        __syncthreads();
    }
    if (t < nb) bsum[t] = tmp[t] - v;
}

__global__ void k_scan3(int* __restrict__ rowptr, int* __restrict__ cursor,
                        const int* __restrict__ bsum, int N) {
    int i = blockIdx.x * 256 + threadIdx.x;
    if (i < N) {
        int v = rowptr[i] + bsum[blockIdx.x];
        rowptr[i] = v;
        cursor[i] = v;
    }
}

// batched fill: 4 edges/thread (measured sweet spot), returning atomics pipelined
__global__ __launch_bounds__(256) void k_fill(const int* __restrict__ ei,
                                              int* __restrict__ cursor,
                                              int* __restrict__ ssrc, int E) {
    int t = blockIdx.x * 256 + threadIdx.x;
    int nt = gridDim.x * 256;
    int s[4], d[4], p[4];
#pragma unroll
    for (int i = 0; i < 4; ++i) {
        int e = t + i * nt;
        if (e < E) { s[i] = ei[e]; d[i] = ei[E + e]; }
    }
#pragma unroll
    for (int i = 0; i < 4; ++i) {
        int e = t + i * nt;
        if (e < E) p[i] = atomicAdd(&cursor[d[i]], 1);
    }
#pragma unroll
    for (int i = 0; i < 4; ++i) {
        int e = t + i * nt;
        if (e < E) ssrc[p[i]] = s[i];
    }
}

// ============ embed GEMM: h = x @ We^T ([N,128] @ [128,64]^T) ============

__global__ __launch_bounds__(256) void k_embed(const float* __restrict__ x,
                                               const float* __restrict__ We,
                                               float* __restrict__ h, int N) {
    __shared__ float Ws[64 * 129];
    __shared__ float xs[32 * 128];
    int tid = threadIdx.x;

#pragma unroll
    for (int i = 0; i < 32; ++i) {
        int m = tid + i * 256;
        Ws[(m >> 7) * 129 + (m & 127)] = We[m];
    }
    int base = blockIdx.x * 32;
    const float4* x4 = (const float4*)(x + (size_t)base * 128);
#pragma unroll
    for (int i = 0; i < 4; ++i) {
        int m = tid + i * 256;
        ((float4*)xs)[m] = x4[m];
    }
    __syncthreads();

    int f = tid & 63, g = tid >> 6;
    float acc[8] = {0, 0, 0, 0, 0, 0, 0, 0};
#pragma unroll 4
    for (int k = 0; k < 128; k += 4) {
        float w0 = Ws[f * 129 + k + 0];
        float w1 = Ws[f * 129 + k + 1];
        float w2 = Ws[f * 129 + k + 2];
        float w3 = Ws[f * 129 + k + 3];
#pragma unroll
        for (int j = 0; j < 8; ++j) {
            const float4 xv = *(const float4*)&xs[(g * 8 + j) * 128 + k];
            acc[j] = fmaf(xv.x, w0, acc[j]);
            acc[j] = fmaf(xv.y, w1, acc[j]);
            acc[j] = fmaf(xv.z, w2, acc[j]);
            acc[j] = fmaf(xv.w, w3, acc[j]);
        }
    }
#pragma unroll
    for (int j = 0; j < 8; ++j) {
        int r = base + g * 8 + j;
        h[(size_t)r * 64 + f] = acc[j];
    }
}

// ============ GCN layer GEMM: tab = fp8_e4m3((act(hin) @ Wg^T) * dinv) ============
// Epilogue: fp32 tile -> LDS -> pack 4 feats/uint with HW cvt -> coalesced store.

__global__ __launch_bounds__(256) void k_gcn(const float* __restrict__ hin,
                                             const float* __restrict__ Wg,
                                             const float* __restrict__ bias_prev, int act,
                                             const float* __restrict__ dinv,
                                             uint32* __restrict__ tab, int N) {
    __shared__ float Ws[64 * 65];
    __shared__ float xs[32 * 64];
    int tid = threadIdx.x;

#pragma unroll
    for (int i = 0; i < 16; ++i) {
        int m = tid + i * 256;
        Ws[(m >> 6) * 65 + (m & 63)] = Wg[m];
    }
    int base = blockIdx.x * 32;
    const float4* hin4 = (const float4*)(hin + (size_t)base * 64);
#pragma unroll
    for (int i = 0; i < 2; ++i) {
        int m = tid + i * 256;
        float4 v = hin4[m];
        if (act) {
            int kf = (m & 15) * 4;
            v.x = fmaxf(v.x + bias_prev[kf + 0], 0.f);
            v.y = fmaxf(v.y + bias_prev[kf + 1], 0.f);
            v.z = fmaxf(v.z + bias_prev[kf + 2], 0.f);
            v.w = fmaxf(v.w + bias_prev[kf + 3], 0.f);
        }
        ((float4*)xs)[m] = v;
    }
    __syncthreads();

    int f = tid & 63, g = tid >> 6;
    float acc[8] = {0, 0, 0, 0, 0, 0, 0, 0};
#pragma unroll 4
    for (int k = 0; k < 64; k += 4) {
        float w0 = Ws[f * 65 + k + 0];
        float w1 = Ws[f * 65 + k + 1];
        float w2 = Ws[f * 65 + k + 2];
        float w3 = Ws[f * 65 + k + 3];
#pragma unroll
        for (int j = 0; j < 8; ++j) {
            const float4 xv = *(const float4*)&xs[(g * 8 + j) * 64 + k];
            acc[j] = fmaf(xv.x, w0, acc[j]);
            acc[j] = fmaf(xv.y, w1, acc[j]);
            acc[j] = fmaf(xv.z, w2, acc[j]);
            acc[j] = fmaf(xv.w, w3, acc[j]);
        }
    }

    // epilogue: stage fp32 result back into xs, then pack to fp8
    __syncthreads();
#pragma unroll
    for (int j = 0; j < 8; ++j) {
        int r = g * 8 + j;
        xs[r * 64 + f] = acc[j] * dinv[base + r];
    }
    __syncthreads();
#pragma unroll
    for (int i = 0; i < 2; ++i) {
        int m = tid + i * 256;          // 512 uints = 32 rows x 16
        int row = m >> 4, idx = m & 15;
        const float4 v = *(const float4*)&xs[row * 64 + idx * 4];
        int u = 0;
        u = __builtin_amdgcn_cvt_pk_fp8_f32(v.x, v.y, u, false);
        u = __builtin_amdgcn_cvt_pk_fp8_f32(v.z, v.w, u, true);
        tab[(size_t)(base + row) * 16 + idx] = u;
    }
}

// ============ fp8 CSR gather-aggregate: one wave per dst, 8 edges/gather ============
// out[d] = dinv[d] * (tab[d] + sum_{e in row d} tab[src_e])
// sub = lane>>3 picks 1 of 8 rows per gather, q = lane&7 picks uint2 (8 fp8 feats)
// of the 64-B row. Edge indices via wave-uniform scalar loads + cndmask tree.

__global__ __launch_bounds__(256) void k_agg(const int* __restrict__ rowptr,
                                             const int* __restrict__ counts,
                                             const int* __restrict__ ssrc,
                                             const float* __restrict__ dinv,
                                             const uint2* __restrict__ tab2,
                                             float* __restrict__ out, int N) {
    int lane = threadIdx.x & 63;
    int d = blockIdx.x * 4 + (threadIdx.x >> 6);
    if (d >= N) return;
    int q = lane & 7;
    int sub = lane >> 3;
    bool b1 = (sub & 1) != 0, b2 = (sub & 2) != 0, b4 = (sub & 4) != 0;

    float a[8] = {0, 0, 0, 0, 0, 0, 0, 0};
    auto accum = [&](uint2 v) {
        floatx2 f01 = __builtin_amdgcn_cvt_pk_f32_fp8((int)v.x, false);
        floatx2 f23 = __builtin_amdgcn_cvt_pk_f32_fp8((int)v.x, true);
        floatx2 f45 = __builtin_amdgcn_cvt_pk_f32_fp8((int)v.y, false);
        floatx2 f67 = __builtin_amdgcn_cvt_pk_f32_fp8((int)v.y, true);
        a[0] += f01.x; a[1] += f01.y; a[2] += f23.x; a[3] += f23.y;
        a[4] += f45.x; a[5] += f45.y; a[6] += f67.x; a[7] += f67.y;
    };

    if (sub == 0) accum(tab2[(size_t)d * 8 + q]);   // self loop counted once

    int beg = __builtin_amdgcn_readfirstlane(rowptr[d]);
    int cnt = __builtin_amdgcn_readfirstlane(counts[d]);
    const int* srow = ssrc + beg;

#define SEL8(e0,e1,e2,e3,e4,e5,e6,e7) \
    (b4 ? (b2 ? (b1 ? e7 : e6) : (b1 ? e5 : e4)) \
        : (b2 ? (b1 ? e3 : e2) : (b1 ? e1 : e0)))

    int j = 0;
    for (; j + 16 <= cnt; j += 16) {
        int e0 = srow[j + 0],  e1 = srow[j + 1],  e2 = srow[j + 2],  e3 = srow[j + 3];
        int e4 = srow[j + 4],  e5 = srow[j + 5],  e6 = srow[j + 6],  e7 = srow[j + 7];
        int e8 = srow[j + 8],  e9 = srow[j + 9],  ea = srow[j + 10], eb = srow[j + 11];
        int ec = srow[j + 12], ed = srow[j + 13], ee = srow[j + 14], ef = srow[j + 15];
        int t0 = SEL8(e0, e1, e2, e3, e4, e5, e6, e7);
        int t1 = SEL8(e8, e9, ea, eb, ec, ed, ee, ef);
        uint2 v0 = tab2[(size_t)t0 * 8 + q];
        uint2 v1 = tab2[(size_t)t1 * 8 + q];
        accum(v0);
        accum(v1);
    }
    int rem = cnt - j;   // 0..15, wave-uniform
    if (rem) {
        // ssrc is padded by 16 ints; OOB positions -> sentinel row N (zeros)
        int e0 = srow[j + 0],  e1 = srow[j + 1],  e2 = srow[j + 2],  e3 = srow[j + 3];
        int e4 = srow[j + 4],  e5 = srow[j + 5],  e6 = srow[j + 6],  e7 = srow[j + 7];
        int t0 = SEL8(e0, e1, e2, e3, e4, e5, e6, e7);
        t0 = (sub < rem) ? t0 : N;
        accum(tab2[(size_t)t0 * 8 + q]);
        if (rem > 8) {
            int e8 = srow[j + 8],  e9 = srow[j + 9],  ea = srow[j + 10], eb = srow[j + 11];
            int ec = srow[j + 12], ed = srow[j + 13], ee = srow[j + 14], ef = srow[j + 15];
            int t1 = SEL8(e8, e9, ea, eb, ec, ed, ee, ef);
            t1 = (sub + 8 < rem) ? t1 : N;
            accum(tab2[(size_t)t1 * 8 + q]);
        }
    }
#undef SEL8

    // reduce across the 8 subs (lanes 8 apart hold the same q)
#pragma unroll
    for (int i = 0; i < 8; ++i) {
        a[i] += __shfl_xor(a[i], 8);
        a[i] += __shfl_xor(a[i], 16);
        a[i] += __shfl_xor(a[i], 32);
    }

    if (sub == 0) {
        float dd = dinv[d];
        float4* o4 = (float4*)out;
        o4[(size_t)d * 16 + 2 * q + 0] = make_float4(dd * a[0], dd * a[1], dd * a[2], dd * a[3]);
        o4[(size_t)d * 16 + 2 * q + 1] = make_float4(dd * a[4], dd * a[5], dd * a[6], dd * a[7]);
    }
}

// ============ centroid squared norms ============

__global__ void k_c2(const float* __restrict__ C, float* __restrict__ c2) {
    int k = threadIdx.x;
    if (k < 100) {
        float s = 0.f;
        for (int d = 0; d < 64; ++d) { float v = C[k * 64 + d]; s = fmaf(v, v, s); }
        c2[k] = s;
    }
}

// ============ centroid distances + pooling: thread = node, quadratic form ============

__global__ __launch_bounds__(256) void k_cent(const float* __restrict__ hin,
                                              const float* __restrict__ b2,
                                              const float* __restrict__ C,
                                              const float* __restrict__ c2g,
                                              float* __restrict__ pooled, int N) {
    __shared__ float pooled_s[128];
    int tid = threadIdx.x;
    if (tid < 128) pooled_s[tid] = 0.f;
    __syncthreads();

    int n = blockIdx.x * 256 + tid;
    bool valid = n < N;

    float h[64];
    float h2 = 0.f;
    {
        const float4* h4 = (const float4*)(hin + ((size_t)(valid ? n : 0) << 6));
#pragma unroll
        for (int i = 0; i < 16; ++i) {
            float4 v = h4[i];
            v.x = fmaxf(v.x + b2[4 * i + 0], 0.f);
            v.y = fmaxf(v.y + b2[4 * i + 1], 0.f);
            v.z = fmaxf(v.z + b2[4 * i + 2], 0.f);
            v.w = fmaxf(v.w + b2[4 * i + 3], 0.f);
            h[4 * i + 0] = v.x; h[4 * i + 1] = v.y;
            h[4 * i + 2] = v.z; h[4 * i + 3] = v.w;
            h2 = fmaf(v.x, v.x, h2); h2 = fmaf(v.y, v.y, h2);
            h2 = fmaf(v.z, v.z, h2); h2 = fmaf(v.w, v.w, h2);
        }
    }

    for (int k = 0; k < 100; ++k) {
        const float* crow = C + k * 64;
        float acc = 0.f;
#pragma unroll
        for (int d = 0; d < 64; ++d) acc = fmaf(h[d], crow[d], acc);
        float d2 = fmaxf(h2 + c2g[k] - 2.f * acc, 0.f);
        float dist = valid ? sqrtf(d2 + 1e-12f) : 0.f;
#pragma unroll
        for (int off = 32; off > 0; off >>= 1) dist += __shfl_xor(dist, off);
        if ((tid & 63) == 0) atomicAdd(&pooled_s[k], dist);
    }
    __syncthreads();
    if (tid < 100) atomicAdd(&pooled[tid], pooled_s[tid]);
}

// ============ output head ============

__global__ void k_out(const float* __restrict__ pooled,
                      const float* __restrict__ Wout,
                      const float* __restrict__ bout,
                      float* __restrict__ out, float invN) {
    int t = threadIdx.x;
    if (t < 10) {
        float s = 0.f;
        for (int k = 0; k < 100; ++k) s += pooled[k] * Wout[t * 100 + k];
        out[t] = s * invN + bout[t];
    }
}

// ============ launcher ============

extern "C" void kernel_launch(void* const* d_in, const int* in_sizes, int n_in,
                              void* d_out, int out_size, void* d_ws, size_t ws_size,
                              hipStream_t stream) {
    const float* x    = (const float*)d_in[0];
    const int*   ei   = (const int*)d_in[1];
    const float* We   = (const float*)d_in[2];
    const float* Wg   = (const float*)d_in[3];
    const float* bg   = (const float*)d_in[4];
    const float* C    = (const float*)d_in[5];
    const float* Wout = (const float*)d_in[6];
    const float* bout = (const float*)d_in[7];
    float*       out  = (float*)d_out;

    const int N = in_sizes[0] / 128;    // 100000
    const int E = in_sizes[1] / 2;      // 1600000
    const int NB = (N + 255) / 256;     // scan blocks (391)

    char* ws = (char*)d_ws;
    size_t off = 0;
    auto alloc = [&](size_t bytes) { void* p = ws + off; off += (bytes + 511) & ~(size_t)511; return p; };
    float*  dinv   = (float*)alloc((size_t)N * 4);
    int*    counts = (int*)  alloc((size_t)N * 4);
    int*    cursor = (int*)  alloc((size_t)N * 4);
    int*    rowptr = (int*)  alloc((size_t)N * 4);
    int*    bsum   = (int*)  alloc((size_t)NB * 4);
    int*    ssrc   = (int*)  alloc((size_t)(E + 16) * 4);     // +16 pad for agg reads
    float*  hA     = (float*)alloc((size_t)N * 64 * 4);
    uint32* tab    = (uint32*)alloc((size_t)(N + 1) * 64);    // fp8 table + sentinel row
    float*  c2     = (float*)alloc(512);
    float*  pooled = (float*)alloc(512);

    hipMemsetAsync(counts, 0, (size_t)N * 4, stream);
    hipMemsetAsync(pooled, 0, 512, stream);
    hipMemsetAsync(tab + (size_t)N * 16, 0, 64, stream);      // sentinel row N = 0

    // CSR build (dst-only)
    k_hist<<<4096, 256, 0, stream>>>(ei + E, counts, E);
    k_scan1<<<NB, 256, 0, stream>>>(counts, rowptr, bsum, dinv, N);
    k_scan2<<<1, 512, 0, stream>>>(bsum, NB);
    k_scan3<<<NB, 256, 0, stream>>>(rowptr, cursor, bsum, N);
    k_fill<<<(E + 1023) / 1024, 256, 0, stream>>>(ei, cursor, ssrc, E);
    k_c2<<<1, 128, 0, stream>>>(C, c2);

    // embed
    k_embed<<<N / 32, 256, 0, stream>>>(x, We, hA, N);

    // 3 GCN layers: gemm (hA -> fp8 tab, scaled by dinv), aggregate (tab -> hA fp32)
    for (int l = 0; l < 3; ++l) {
        const float* bias_prev = (l == 0) ? bg : (bg + (l - 1) * 64);
        int act = (l == 0) ? 0 : 1;
        k_gcn<<<N / 32, 256, 0, stream>>>(hA, Wg + (size_t)l * 64 * 64, bias_prev, act,
                                          dinv, tab, N);
        k_agg<<<(N + 3) / 4, 256, 0, stream>>>(rowptr, counts, ssrc, dinv,
                                               (const uint2*)tab, hA, N);
    }

    // centroid distances + pooling (applies relu + b_gcn[2])
    k_cent<<<NB, 256, 0, stream>>>(hA, bg + 2 * 64, C, c2, pooled, N);

    // head
    k_out<<<1, 64, 0, stream>>>(pooled, Wout, bout, out, 1.0f / (float)N);
}

// Round 11
// 479.812 us; speedup vs baseline: 1.5032x; 1.1986x over previous
//
#include <hip/hip_runtime.h>
#include <hip/hip_bf16.h>

typedef unsigned int uint32;
typedef float floatx2 __attribute__((ext_vector_type(2)));

#define CHUNK 16384

// ============ bucketed CSR build (dst>>8 buckets, LDS-atomic sort) ============

// pass A: per-chunk bucket histogram
__global__ __launch_bounds__(256) void k_bhist(const int* __restrict__ dst,
                                               int* __restrict__ bcnt,
                                               int E, int NBUCK, int NCH) {
    __shared__ int h[512];
    int c = blockIdx.x, tid = threadIdx.x;
    for (int i = tid; i < NBUCK; i += 256) h[i] = 0;
    __syncthreads();
    int base = c * CHUNK;
#pragma unroll
    for (int k = 0; k < CHUNK / 256; ++k) {
        int e = base + k * 256 + tid;
        if (e < E) atomicAdd(&h[dst[e] >> 8], 1);
    }
    __syncthreads();
    for (int i = tid; i < NBUCK; i += 256) bcnt[(size_t)i * NCH + c] = h[i];
}

// pass A2: per-bucket exclusive scan over chunks (NCH <= 128)
__global__ __launch_bounds__(128) void k_bscan1(const int* __restrict__ bcnt,
                                                int* __restrict__ bofs,
                                                int* __restrict__ btot, int NCH) {
    __shared__ int tmp[128];
    int b = blockIdx.x, t = threadIdx.x;
    int v = (t < NCH) ? bcnt[(size_t)b * NCH + t] : 0;
    tmp[t] = v;
    __syncthreads();
    for (int off = 1; off < 128; off <<= 1) {
        int u = (t >= off) ? tmp[t - off] : 0;
        __syncthreads();
        tmp[t] += u;
        __syncthreads();
    }
    if (t < NCH) bofs[(size_t)b * NCH + t] = tmp[t] - v;
    if (t == 127) btot[b] = tmp[127];
}

// pass A3: exclusive scan of bucket totals (nb <= 512); bbase[nb] = E
__global__ __launch_bounds__(512) void k_bscan2(const int* __restrict__ btot,
                                                int* __restrict__ bbase, int nb) {
    __shared__ int tmp[512];
    int t = threadIdx.x;
    int v = (t < nb) ? btot[t] : 0;
    tmp[t] = v;
    __syncthreads();
    for (int off = 1; off < 512; off <<= 1) {
        int u = (t >= off) ? tmp[t - off] : 0;
        __syncthreads();
        tmp[t] += u;
        __syncthreads();
    }
    if (t < nb) bbase[t] = tmp[t] - v;
    if (t == nb - 1) bbase[nb] = tmp[t];
}

// pass B: scatter packed (src | dlow<<20) into bucket-contiguous runs, LDS cursors
__global__ __launch_bounds__(256) void k_bscatter(const int* __restrict__ ei,
                                                  const int* __restrict__ bbase,
                                                  const int* __restrict__ bofs,
                                                  uint32* __restrict__ ebuf,
                                                  int E, int NBUCK, int NCH) {
    __shared__ int cur[512];
    int c = blockIdx.x, tid = threadIdx.x;
    for (int i = tid; i < NBUCK; i += 256)
        cur[i] = bbase[i] + bofs[(size_t)i * NCH + c];
    __syncthreads();
    int base = c * CHUNK;
#pragma unroll
    for (int k = 0; k < CHUNK / 256; ++k) {
        int e = base + k * 256 + tid;
        if (e < E) {
            int s = ei[e];
            int d = ei[E + e];
            int p = atomicAdd(&cur[d >> 8], 1);
            ebuf[p] = (uint32)s | ((uint32)(d & 255) << 20);
        }
    }
}

// pass C: one block per bucket — 256-way LDS histogram/scan, emit rowptr/counts/
// dinv, scatter src to final CSR position (writes stay in a 16-KB L2 window)
__global__ __launch_bounds__(256) void k_bsort(const uint32* __restrict__ ebuf,
                                               const int* __restrict__ bbase,
                                               int* __restrict__ ssrc,
                                               int* __restrict__ rowptr,
                                               int* __restrict__ counts,
                                               float* __restrict__ dinv, int N) {
    __shared__ int h[256];
    __shared__ int sc[256];
    __shared__ int cur[256];
    int b = blockIdx.x, tid = threadIdx.x;
    int beg = bbase[b], end = bbase[b + 1];
    h[tid] = 0;
    __syncthreads();
    for (int j = beg + tid; j < end; j += 256)
        atomicAdd(&h[(ebuf[j] >> 20) & 255], 1);
    __syncthreads();
    int v = h[tid];
    sc[tid] = v;
    __syncthreads();
    for (int off = 1; off < 256; off <<= 1) {
        int u = (tid >= off) ? sc[tid - off] : 0;
        __syncthreads();
        sc[tid] += u;
        __syncthreads();
    }
    int rowbase = beg + sc[tid] - v;   // exclusive
    cur[tid] = rowbase;
    int d = b * 256 + tid;
    if (d < N) {
        rowptr[d] = rowbase;
        counts[d] = v;
        dinv[d] = rsqrtf((float)(v + 1));   // +1 self loop
    }
    __syncthreads();
    for (int j = beg + tid; j < end; j += 256) {
        uint32 w = ebuf[j];
        int p = atomicAdd(&cur[(w >> 20) & 255], 1);
        ssrc[p] = (int)(w & 0xFFFFFu);
    }
}

// ============ embed GEMM: h = x @ We^T ([N,128] @ [128,64]^T) ============

__global__ __launch_bounds__(256) void k_embed(const float* __restrict__ x,
                                               const float* __restrict__ We,
                                               float* __restrict__ h, int N) {
    __shared__ float Ws[64 * 129];
    __shared__ float xs[32 * 128];
    int tid = threadIdx.x;

#pragma unroll
    for (int i = 0; i < 32; ++i) {
        int m = tid + i * 256;
        Ws[(m >> 7) * 129 + (m & 127)] = We[m];
    }
    int base = blockIdx.x * 32;
    const float4* x4 = (const float4*)(x + (size_t)base * 128);
#pragma unroll
    for (int i = 0; i < 4; ++i) {
        int m = tid + i * 256;
        ((float4*)xs)[m] = x4[m];
    }
    __syncthreads();

    int f = tid & 63, g = tid >> 6;
    float acc[8] = {0, 0, 0, 0, 0, 0, 0, 0};
#pragma unroll 4
    for (int k = 0; k < 128; k += 4) {
        float w0 = Ws[f * 129 + k + 0];
        float w1 = Ws[f * 129 + k + 1];
        float w2 = Ws[f * 129 + k + 2];
        float w3 = Ws[f * 129 + k + 3];
#pragma unroll
        for (int j = 0; j < 8; ++j) {
            const float4 xv = *(const float4*)&xs[(g * 8 + j) * 128 + k];
            acc[j] = fmaf(xv.x, w0, acc[j]);
            acc[j] = fmaf(xv.y, w1, acc[j]);
            acc[j] = fmaf(xv.z, w2, acc[j]);
            acc[j] = fmaf(xv.w, w3, acc[j]);
        }
    }
#pragma unroll
    for (int j = 0; j < 8; ++j) {
        int r = base + g * 8 + j;
        h[(size_t)r * 64 + f] = acc[j];
    }
}

// ============ GCN layer GEMM: tab = fp8_e4m3((act(hin) @ Wg^T) * dinv) ============

__global__ __launch_bounds__(256) void k_gcn(const float* __restrict__ hin,
                                             const float* __restrict__ Wg,
                                             const float* __restrict__ bias_prev, int act,
                                             const float* __restrict__ dinv,
                                             uint32* __restrict__ tab, int N) {
    __shared__ float Ws[64 * 65];
    __shared__ float xs[32 * 64];
    int tid = threadIdx.x;

#pragma unroll
    for (int i = 0; i < 16; ++i) {
        int m = tid + i * 256;
        Ws[(m >> 6) * 65 + (m & 63)] = Wg[m];
    }
    int base = blockIdx.x * 32;
    const float4* hin4 = (const float4*)(hin + (size_t)base * 64);
#pragma unroll
    for (int i = 0; i < 2; ++i) {
        int m = tid + i * 256;
        float4 v = hin4[m];
        if (act) {
            int kf = (m & 15) * 4;
            v.x = fmaxf(v.x + bias_prev[kf + 0], 0.f);
            v.y = fmaxf(v.y + bias_prev[kf + 1], 0.f);
            v.z = fmaxf(v.z + bias_prev[kf + 2], 0.f);
            v.w = fmaxf(v.w + bias_prev[kf + 3], 0.f);
        }
        ((float4*)xs)[m] = v;
    }
    __syncthreads();

    int f = tid & 63, g = tid >> 6;
    float acc[8] = {0, 0, 0, 0, 0, 0, 0, 0};
#pragma unroll 4
    for (int k = 0; k < 64; k += 4) {
        float w0 = Ws[f * 65 + k + 0];
        float w1 = Ws[f * 65 + k + 1];
        float w2 = Ws[f * 65 + k + 2];
        float w3 = Ws[f * 65 + k + 3];
#pragma unroll
        for (int j = 0; j < 8; ++j) {
            const float4 xv = *(const float4*)&xs[(g * 8 + j) * 64 + k];
            acc[j] = fmaf(xv.x, w0, acc[j]);
            acc[j] = fmaf(xv.y, w1, acc[j]);
            acc[j] = fmaf(xv.z, w2, acc[j]);
            acc[j] = fmaf(xv.w, w3, acc[j]);
        }
    }

    // epilogue: stage fp32 result back into xs, then pack to fp8
    __syncthreads();
#pragma unroll
    for (int j = 0; j < 8; ++j) {
        int r = g * 8 + j;
        xs[r * 64 + f] = acc[j] * dinv[base + r];
    }
    __syncthreads();
#pragma unroll
    for (int i = 0; i < 2; ++i) {
        int m = tid + i * 256;          // 512 uints = 32 rows x 16
        int row = m >> 4, idx = m & 15;
        const float4 v = *(const float4*)&xs[row * 64 + idx * 4];
        int u = 0;
        u = __builtin_amdgcn_cvt_pk_fp8_f32(v.x, v.y, u, false);
        u = __builtin_amdgcn_cvt_pk_fp8_f32(v.z, v.w, u, true);
        tab[(size_t)(base + row) * 16 + idx] = u;
    }
}

// ============ fp8 CSR gather-aggregate: one wave per dst, 8 edges/gather ============

__global__ __launch_bounds__(256) void k_agg(const int* __restrict__ rowptr,
                                             const int* __restrict__ counts,
                                             const int* __restrict__ ssrc,
                                             const float* __restrict__ dinv,
                                             const uint2* __restrict__ tab2,
                                             float* __restrict__ out, int N) {
    int lane = threadIdx.x & 63;
    int d = blockIdx.x * 4 + (threadIdx.x >> 6);
    if (d >= N) return;
    int q = lane & 7;
    int sub = lane >> 3;
    bool b1 = (sub & 1) != 0, b2 = (sub & 2) != 0, b4 = (sub & 4) != 0;

    float a[8] = {0, 0, 0, 0, 0, 0, 0, 0};
    auto accum = [&](uint2 v) {
        floatx2 f01 = __builtin_amdgcn_cvt_pk_f32_fp8((int)v.x, false);
        floatx2 f23 = __builtin_amdgcn_cvt_pk_f32_fp8((int)v.x, true);
        floatx2 f45 = __builtin_amdgcn_cvt_pk_f32_fp8((int)v.y, false);
        floatx2 f67 = __builtin_amdgcn_cvt_pk_f32_fp8((int)v.y, true);
        a[0] += f01.x; a[1] += f01.y; a[2] += f23.x; a[3] += f23.y;
        a[4] += f45.x; a[5] += f45.y; a[6] += f67.x; a[7] += f67.y;
    };

    if (sub == 0) accum(tab2[(size_t)d * 8 + q]);   // self loop counted once

    int beg = __builtin_amdgcn_readfirstlane(rowptr[d]);
    int cnt = __builtin_amdgcn_readfirstlane(counts[d]);
    const int* srow = ssrc + beg;

#define SEL8(e0,e1,e2,e3,e4,e5,e6,e7) \
    (b4 ? (b2 ? (b1 ? e7 : e6) : (b1 ? e5 : e4)) \
        : (b2 ? (b1 ? e3 : e2) : (b1 ? e1 : e0)))

    int j = 0;
    for (; j + 16 <= cnt; j += 16) {
        int e0 = srow[j + 0],  e1 = srow[j + 1],  e2 = srow[j + 2],  e3 = srow[j + 3];
        int e4 = srow[j + 4],  e5 = srow[j + 5],  e6 = srow[j + 6],  e7 = srow[j + 7];
        int e8 = srow[j + 8],  e9 = srow[j + 9],  ea = srow[j + 10], eb = srow[j + 11];
        int ec = srow[j + 12], ed = srow[j + 13], ee = srow[j + 14], ef = srow[j + 15];
        int t0 = SEL8(e0, e1, e2, e3, e4, e5, e6, e7);
        int t1 = SEL8(e8, e9, ea, eb, ec, ed, ee, ef);
        uint2 v0 = tab2[(size_t)t0 * 8 + q];
        uint2 v1 = tab2[(size_t)t1 * 8 + q];
        accum(v0);
        accum(v1);
    }
    int rem = cnt - j;   // 0..15, wave-uniform
    if (rem) {
        // ssrc padded by 16 ints; OOB lanes -> sentinel row N (zeros)
        int e0 = srow[j + 0],  e1 = srow[j + 1],  e2 = srow[j + 2],  e3 = srow[j + 3];
        int e4 = srow[j + 4],  e5 = srow[j + 5],  e6 = srow[j + 6],  e7 = srow[j + 7];
        int t0 = SEL8(e0, e1, e2, e3, e4, e5, e6, e7);
        t0 = (sub < rem) ? t0 : N;
        accum(tab2[(size_t)t0 * 8 + q]);
        if (rem > 8) {
            int e8 = srow[j + 8],  e9 = srow[j + 9],  ea = srow[j + 10], eb = srow[j + 11];
            int ec = srow[j + 12], ed = srow[j + 13], ee = srow[j + 14], ef = srow[j + 15];
            int t1 = SEL8(e8, e9, ea, eb, ec, ed, ee, ef);
            t1 = (sub + 8 < rem) ? t1 : N;
            accum(tab2[(size_t)t1 * 8 + q]);
        }
    }
#undef SEL8

    // reduce across the 8 subs (lanes 8 apart hold the same q)
#pragma unroll
    for (int i = 0; i < 8; ++i) {
        a[i] += __shfl_xor(a[i], 8);
        a[i] += __shfl_xor(a[i], 16);
        a[i] += __shfl_xor(a[i], 32);
    }

    if (sub == 0) {
        float dd = dinv[d];
        float4* o4 = (float4*)out;
        o4[(size_t)d * 16 + 2 * q + 0] = make_float4(dd * a[0], dd * a[1], dd * a[2], dd * a[3]);
        o4[(size_t)d * 16 + 2 * q + 1] = make_float4(dd * a[4], dd * a[5], dd * a[6], dd * a[7]);
    }
}

// ============ centroid squared norms ============

__global__ void k_c2(const float* __restrict__ C, float* __restrict__ c2) {
    int k = threadIdx.x;
    if (k < 100) {
        float s = 0.f;
        for (int d = 0; d < 64; ++d) { float v = C[k * 64 + d]; s = fmaf(v, v, s); }
        c2[k] = s;
    }
}

// ============ centroid distances + pooling: thread = node, quadratic form ============

__global__ __launch_bounds__(256) void k_cent(const float* __restrict__ hin,
                                              const float* __restrict__ b2,
                                              const float* __restrict__ C,
                                              const float* __restrict__ c2g,
                                              float* __restrict__ pooled, int N) {
    __shared__ float pooled_s[128];
    int tid = threadIdx.x;
    if (tid < 128) pooled_s[tid] = 0.f;
    __syncthreads();

    int n = blockIdx.x * 256 + tid;
    bool valid = n < N;

    float h[64];
    float h2 = 0.f;
    {
        const float4* h4 = (const float4*)(hin + ((size_t)(valid ? n : 0) << 6));
#pragma unroll
        for (int i = 0; i < 16; ++i) {
            float4 v = h4[i];
            v.x = fmaxf(v.x + b2[4 * i + 0], 0.f);
            v.y = fmaxf(v.y + b2[4 * i + 1], 0.f);
            v.z = fmaxf(v.z + b2[4 * i + 2], 0.f);
            v.w = fmaxf(v.w + b2[4 * i + 3], 0.f);
            h[4 * i + 0] = v.x; h[4 * i + 1] = v.y;
            h[4 * i + 2] = v.z; h[4 * i + 3] = v.w;
            h2 = fmaf(v.x, v.x, h2); h2 = fmaf(v.y, v.y, h2);
            h2 = fmaf(v.z, v.z, h2); h2 = fmaf(v.w, v.w, h2);
        }
    }

    for (int k = 0; k < 100; ++k) {
        const float* crow = C + k * 64;
        float acc = 0.f;
#pragma unroll
        for (int d = 0; d < 64; ++d) acc = fmaf(h[d], crow[d], acc);
        float d2 = fmaxf(h2 + c2g[k] - 2.f * acc, 0.f);
        float dist = valid ? sqrtf(d2 + 1e-12f) : 0.f;
#pragma unroll
        for (int off = 32; off > 0; off >>= 1) dist += __shfl_xor(dist, off);
        if ((tid & 63) == 0) atomicAdd(&pooled_s[k], dist);
    }
    __syncthreads();
    if (tid < 100) atomicAdd(&pooled[tid], pooled_s[tid]);
}

// ============ output head ============

__global__ void k_out(const float* __restrict__ pooled,
                      const float* __restrict__ Wout,
                      const float* __restrict__ bout,
                      float* __restrict__ out, float invN) {
    int t = threadIdx.x;
    if (t < 10) {
        float s = 0.f;
        for (int k = 0; k < 100; ++k) s += pooled[k] * Wout[t * 100 + k];
        out[t] = s * invN + bout[t];
    }
}

// ============ launcher ============

extern "C" void kernel_launch(void* const* d_in, const int* in_sizes, int n_in,
                              void* d_out, int out_size, void* d_ws, size_t ws_size,
                              hipStream_t stream) {
    const float* x    = (const float*)d_in[0];
    const int*   ei   = (const int*)d_in[1];
    const float* We   = (const float*)d_in[2];
    const float* Wg   = (const float*)d_in[3];
    const float* bg   = (const float*)d_in[4];
    const float* C    = (const float*)d_in[5];
    const float* Wout = (const float*)d_in[6];
    const float* bout = (const float*)d_in[7];
    float*       out  = (float*)d_out;

    const int N = in_sizes[0] / 128;          // 100000
    const int E = in_sizes[1] / 2;            // 1600000
    const int NBUCK = (N + 255) >> 8;         // 391 dst-buckets
    const int NCH = (E + CHUNK - 1) / CHUNK;  // 98 chunks
    const int NBN = (N + 255) / 256;

    char* ws = (char*)d_ws;
    size_t off = 0;
    auto alloc = [&](size_t bytes) { void* p = ws + off; off += (bytes + 511) & ~(size_t)511; return p; };
    float*  dinv   = (float*)alloc((size_t)N * 4);
    int*    counts = (int*)  alloc((size_t)N * 4);
    int*    rowptr = (int*)  alloc((size_t)N * 4);
    int*    bcnt   = (int*)  alloc((size_t)NBUCK * NCH * 4);
    int*    bofs   = (int*)  alloc((size_t)NBUCK * NCH * 4);
    int*    btot   = (int*)  alloc((size_t)NBUCK * 4);
    int*    bbase  = (int*)  alloc((size_t)(NBUCK + 1) * 4);
    uint32* ebuf   = (uint32*)alloc((size_t)E * 4);
    int*    ssrc   = (int*)  alloc((size_t)(E + 16) * 4);     // +16 pad for agg reads
    float*  hA     = (float*)alloc((size_t)N * 64 * 4);
    uint32* tab    = (uint32*)alloc((size_t)(N + 1) * 64);    // fp8 table + sentinel row
    float*  c2     = (float*)alloc(512);
    float*  pooled = (float*)alloc(512);

    hipMemsetAsync(pooled, 0, 512, stream);
    hipMemsetAsync(tab + (size_t)N * 16, 0, 64, stream);      // sentinel row N = 0

    // bucketed CSR build (no global atomics)
    k_bhist<<<NCH, 256, 0, stream>>>(ei + E, bcnt, E, NBUCK, NCH);
    k_bscan1<<<NBUCK, 128, 0, stream>>>(bcnt, bofs, btot, NCH);
    k_bscan2<<<1, 512, 0, stream>>>(btot, bbase, NBUCK);
    k_bscatter<<<NCH, 256, 0, stream>>>(ei, bbase, bofs, ebuf, E, NBUCK, NCH);
    k_bsort<<<NBUCK, 256, 0, stream>>>(ebuf, bbase, ssrc, rowptr, counts, dinv, N);
    k_c2<<<1, 128, 0, stream>>>(C, c2);

    // embed
    k_embed<<<N / 32, 256, 0, stream>>>(x, We, hA, N);

    // 3 GCN layers: gemm (hA -> fp8 tab, scaled by dinv), aggregate (tab -> hA fp32)
    for (int l = 0; l < 3; ++l) {
        const float* bias_prev = (l == 0) ? bg : (bg + (l - 1) * 64);
        int act = (l == 0) ? 0 : 1;
        k_gcn<<<N / 32, 256, 0, stream>>>(hA, Wg + (size_t)l * 64 * 64, bias_prev, act,
                                          dinv, tab, N);
        k_agg<<<(N + 3) / 4, 256, 0, stream>>>(rowptr, counts, ssrc, dinv,
                                               (const uint2*)tab, hA, N);
    }

    // centroid distances + pooling (applies relu + b_gcn[2])
    k_cent<<<NBN, 256, 0, stream>>>(hA, bg + 2 * 64, C, c2, pooled, N);

    // head
    k_out<<<1, 64, 0, stream>>>(pooled, Wout, bout, out, 1.0f / (float)N);
}

// Round 12
// 461.772 us; speedup vs baseline: 1.5619x; 1.0391x over previous
//
#include <hip/hip_runtime.h>
#include <hip/hip_bf16.h>

typedef unsigned int uint32;
typedef float floatx2 __attribute__((ext_vector_type(2)));

#define CHUNK 16384

// ============ bucketed CSR build (dst>>8 buckets, LDS-atomic sort) ============

__global__ __launch_bounds__(256) void k_bhist(const int* __restrict__ dst,
                                               int* __restrict__ bcnt,
                                               int E, int NBUCK, int NCH) {
    __shared__ int h[512];
    int c = blockIdx.x, tid = threadIdx.x;
    for (int i = tid; i < NBUCK; i += 256) h[i] = 0;
    __syncthreads();
    int base = c * CHUNK;
#pragma unroll
    for (int k = 0; k < CHUNK / 256; ++k) {
        int e = base + k * 256 + tid;
        if (e < E) atomicAdd(&h[dst[e] >> 8], 1);
    }
    __syncthreads();
    for (int i = tid; i < NBUCK; i += 256) bcnt[(size_t)i * NCH + c] = h[i];
}

__global__ __launch_bounds__(128) void k_bscan1(const int* __restrict__ bcnt,
                                                int* __restrict__ bofs,
                                                int* __restrict__ btot, int NCH) {
    __shared__ int tmp[128];
    int b = blockIdx.x, t = threadIdx.x;
    int v = (t < NCH) ? bcnt[(size_t)b * NCH + t] : 0;
    tmp[t] = v;
    __syncthreads();
    for (int off = 1; off < 128; off <<= 1) {
        int u = (t >= off) ? tmp[t - off] : 0;
        __syncthreads();
        tmp[t] += u;
        __syncthreads();
    }
    if (t < NCH) bofs[(size_t)b * NCH + t] = tmp[t] - v;
    if (t == 127) btot[b] = tmp[127];
}

__global__ __launch_bounds__(512) void k_bscan2(const int* __restrict__ btot,
                                                int* __restrict__ bbase, int nb) {
    __shared__ int tmp[512];
    int t = threadIdx.x;
    int v = (t < nb) ? btot[t] : 0;
    tmp[t] = v;
    __syncthreads();
    for (int off = 1; off < 512; off <<= 1) {
        int u = (t >= off) ? tmp[t - off] : 0;
        __syncthreads();
        tmp[t] += u;
        __syncthreads();
    }
    if (t < nb) bbase[t] = tmp[t] - v;
    if (t == nb - 1) bbase[nb] = tmp[t];
}

__global__ __launch_bounds__(256) void k_bscatter(const int* __restrict__ ei,
                                                  const int* __restrict__ bbase,
                                                  const int* __restrict__ bofs,
                                                  uint32* __restrict__ ebuf,
                                                  int E, int NBUCK, int NCH) {
    __shared__ int cur[512];
    int c = blockIdx.x, tid = threadIdx.x;
    for (int i = tid; i < NBUCK; i += 256)
        cur[i] = bbase[i] + bofs[(size_t)i * NCH + c];
    __syncthreads();
    int base = c * CHUNK;
#pragma unroll
    for (int k = 0; k < CHUNK / 256; ++k) {
        int e = base + k * 256 + tid;
        if (e < E) {
            int s = ei[e];
            int d = ei[E + e];
            int p = atomicAdd(&cur[d >> 8], 1);
            ebuf[p] = (uint32)s | ((uint32)(d & 255) << 20);
        }
    }
}

__global__ __launch_bounds__(256) void k_bsort(const uint32* __restrict__ ebuf,
                                               const int* __restrict__ bbase,
                                               int* __restrict__ ssrc,
                                               int* __restrict__ rowptr,
                                               int* __restrict__ counts,
                                               float* __restrict__ dinv, int N) {
    __shared__ int h[256];
    __shared__ int sc[256];
    __shared__ int cur[256];
    int b = blockIdx.x, tid = threadIdx.x;
    int beg = bbase[b], end = bbase[b + 1];
    h[tid] = 0;
    __syncthreads();
    for (int j = beg + tid; j < end; j += 256)
        atomicAdd(&h[(ebuf[j] >> 20) & 255], 1);
    __syncthreads();
    int v = h[tid];
    sc[tid] = v;
    __syncthreads();
    for (int off = 1; off < 256; off <<= 1) {
        int u = (tid >= off) ? sc[tid - off] : 0;
        __syncthreads();
        sc[tid] += u;
        __syncthreads();
    }
    int rowbase = beg + sc[tid] - v;
    cur[tid] = rowbase;
    int d = b * 256 + tid;
    if (d < N) {
        rowptr[d] = rowbase;
        counts[d] = v;
        dinv[d] = rsqrtf((float)(v + 1));   // +1 self loop
    }
    __syncthreads();
    for (int j = beg + tid; j < end; j += 256) {
        uint32 w = ebuf[j];
        int p = atomicAdd(&cur[(w >> 20) & 255], 1);
        ssrc[p] = (int)(w & 0xFFFFFu);
    }
}

// ============ embed GEMM: h = x @ We^T ([N,128] @ [128,64]^T) ============

__global__ __launch_bounds__(256) void k_embed(const float* __restrict__ x,
                                               const float* __restrict__ We,
                                               float* __restrict__ h, int N) {
    __shared__ float Ws[64 * 129];
    __shared__ float xs[32 * 128];
    int tid = threadIdx.x;

#pragma unroll
    for (int i = 0; i < 32; ++i) {
        int m = tid + i * 256;
        Ws[(m >> 7) * 129 + (m & 127)] = We[m];
    }
    int base = blockIdx.x * 32;
    const float4* x4 = (const float4*)(x + (size_t)base * 128);
#pragma unroll
    for (int i = 0; i < 4; ++i) {
        int m = tid + i * 256;
        ((float4*)xs)[m] = x4[m];
    }
    __syncthreads();

    int f = tid & 63, g = tid >> 6;
    float acc[8] = {0, 0, 0, 0, 0, 0, 0, 0};
#pragma unroll 4
    for (int k = 0; k < 128; k += 4) {
        float w0 = Ws[f * 129 + k + 0];
        float w1 = Ws[f * 129 + k + 1];
        float w2 = Ws[f * 129 + k + 2];
        float w3 = Ws[f * 129 + k + 3];
#pragma unroll
        for (int j = 0; j < 8; ++j) {
            const float4 xv = *(const float4*)&xs[(g * 8 + j) * 128 + k];
            acc[j] = fmaf(xv.x, w0, acc[j]);
            acc[j] = fmaf(xv.y, w1, acc[j]);
            acc[j] = fmaf(xv.z, w2, acc[j]);
            acc[j] = fmaf(xv.w, w3, acc[j]);
        }
    }
#pragma unroll
    for (int j = 0; j < 8; ++j) {
        int r = base + g * 8 + j;
        h[(size_t)r * 64 + f] = acc[j];
    }
}

// ============ GCN layer GEMM: tab = fp8_e4m3((act(hin) @ Wg^T) * dinv) ============

__global__ __launch_bounds__(256) void k_gcn(const float* __restrict__ hin,
                                             const float* __restrict__ Wg,
                                             const float* __restrict__ bias_prev, int act,
                                             const float* __restrict__ dinv,
                                             uint32* __restrict__ tab, int N) {
    __shared__ float Ws[64 * 65];
    __shared__ float xs[32 * 64];
    int tid = threadIdx.x;

#pragma unroll
    for (int i = 0; i < 16; ++i) {
        int m = tid + i * 256;
        Ws[(m >> 6) * 65 + (m & 63)] = Wg[m];
    }
    int base = blockIdx.x * 32;
    const float4* hin4 = (const float4*)(hin + (size_t)base * 64);
#pragma unroll
    for (int i = 0; i < 2; ++i) {
        int m = tid + i * 256;
        float4 v = hin4[m];
        if (act) {
            int kf = (m & 15) * 4;
            v.x = fmaxf(v.x + bias_prev[kf + 0], 0.f);
            v.y = fmaxf(v.y + bias_prev[kf + 1], 0.f);
            v.z = fmaxf(v.z + bias_prev[kf + 2], 0.f);
            v.w = fmaxf(v.w + bias_prev[kf + 3], 0.f);
        }
        ((float4*)xs)[m] = v;
    }
    __syncthreads();

    int f = tid & 63, g = tid >> 6;
    float acc[8] = {0, 0, 0, 0, 0, 0, 0, 0};
#pragma unroll 4
    for (int k = 0; k < 64; k += 4) {
        float w0 = Ws[f * 65 + k + 0];
        float w1 = Ws[f * 65 + k + 1];
        float w2 = Ws[f * 65 + k + 2];
        float w3 = Ws[f * 65 + k + 3];
#pragma unroll
        for (int j = 0; j < 8; ++j) {
            const float4 xv = *(const float4*)&xs[(g * 8 + j) * 64 + k];
            acc[j] = fmaf(xv.x, w0, acc[j]);
            acc[j] = fmaf(xv.y, w1, acc[j]);
            acc[j] = fmaf(xv.z, w2, acc[j]);
            acc[j] = fmaf(xv.w, w3, acc[j]);
        }
    }

    // epilogue: stage fp32 result back into xs, then pack to fp8
    __syncthreads();
#pragma unroll
    for (int j = 0; j < 8; ++j) {
        int r = g * 8 + j;
        xs[r * 64 + f] = acc[j] * dinv[base + r];
    }
    __syncthreads();
#pragma unroll
    for (int i = 0; i < 2; ++i) {
        int m = tid + i * 256;          // 512 uints = 32 rows x 16
        int row = m >> 4, idx = m & 15;
        const float4 v = *(const float4*)&xs[row * 64 + idx * 4];
        int u = 0;
        u = __builtin_amdgcn_cvt_pk_fp8_f32(v.x, v.y, u, false);
        u = __builtin_amdgcn_cvt_pk_fp8_f32(v.z, v.w, u, true);
        tab[(size_t)(base + row) * 16 + idx] = u;
    }
}

// ============ fp8 CSR gather-aggregate: one wave per dst, 8 edges/gather ============

__global__ __launch_bounds__(256) void k_agg(const int* __restrict__ rowptr,
                                             const int* __restrict__ counts,
                                             const int* __restrict__ ssrc,
                                             const float* __restrict__ dinv,
                                             const uint2* __restrict__ tab2,
                                             float* __restrict__ out, int N) {
    int lane = threadIdx.x & 63;
    int d = blockIdx.x * 4 + (threadIdx.x >> 6);
    if (d >= N) return;
    int q = lane & 7;
    int sub = lane >> 3;
    bool b1 = (sub & 1) != 0, b2 = (sub & 2) != 0, b4 = (sub & 4) != 0;

    float a[8] = {0, 0, 0, 0, 0, 0, 0, 0};
    auto accum = [&](uint2 v) {
        floatx2 f01 = __builtin_amdgcn_cvt_pk_f32_fp8((int)v.x, false);
        floatx2 f23 = __builtin_amdgcn_cvt_pk_f32_fp8((int)v.x, true);
        floatx2 f45 = __builtin_amdgcn_cvt_pk_f32_fp8((int)v.y, false);
        floatx2 f67 = __builtin_amdgcn_cvt_pk_f32_fp8((int)v.y, true);
        a[0] += f01.x; a[1] += f01.y; a[2] += f23.x; a[3] += f23.y;
        a[4] += f45.x; a[5] += f45.y; a[6] += f67.x; a[7] += f67.y;
    };

    if (sub == 0) accum(tab2[(size_t)d * 8 + q]);   // self loop counted once

    int beg = __builtin_amdgcn_readfirstlane(rowptr[d]);
    int cnt = __builtin_amdgcn_readfirstlane(counts[d]);
    const int* srow = ssrc + beg;

#define SEL8(e0,e1,e2,e3,e4,e5,e6,e7) \
    (b4 ? (b2 ? (b1 ? e7 : e6) : (b1 ? e5 : e4)) \
        : (b2 ? (b1 ? e3 : e2) : (b1 ? e1 : e0)))

    int j = 0;
    for (; j + 16 <= cnt; j += 16) {
        int e0 = srow[j + 0],  e1 = srow[j + 1],  e2 = srow[j + 2],  e3 = srow[j + 3];
        int e4 = srow[j + 4],  e5 = srow[j + 5],  e6 = srow[j + 6],  e7 = srow[j + 7];
        int e8 = srow[j + 8],  e9 = srow[j + 9],  ea = srow[j + 10], eb = srow[j + 11];
        int ec = srow[j + 12], ed = srow[j + 13], ee = srow[j + 14], ef = srow[j + 15];
        int t0 = SEL8(e0, e1, e2, e3, e4, e5, e6, e7);
        int t1 = SEL8(e8, e9, ea, eb, ec, ed, ee, ef);
        uint2 v0 = tab2[(size_t)t0 * 8 + q];
        uint2 v1 = tab2[(size_t)t1 * 8 + q];
        accum(v0);
        accum(v1);
    }
    int rem = cnt - j;   // 0..15, wave-uniform
    if (rem) {
        int e0 = srow[j + 0],  e1 = srow[j + 1],  e2 = srow[j + 2],  e3 = srow[j + 3];
        int e4 = srow[j + 4],  e5 = srow[j + 5],  e6 = srow[j + 6],  e7 = srow[j + 7];
        int t0 = SEL8(e0, e1, e2, e3, e4, e5, e6, e7);
        t0 = (sub < rem) ? t0 : N;
        accum(tab2[(size_t)t0 * 8 + q]);
        if (rem > 8) {
            int e8 = srow[j + 8],  e9 = srow[j + 9],  ea = srow[j + 10], eb = srow[j + 11];
            int ec = srow[j + 12], ed = srow[j + 13], ee = srow[j + 14], ef = srow[j + 15];
            int t1 = SEL8(e8, e9, ea, eb, ec, ed, ee, ef);
            t1 = (sub + 8 < rem) ? t1 : N;
            accum(tab2[(size_t)t1 * 8 + q]);
        }
    }
#undef SEL8

#pragma unroll
    for (int i = 0; i < 8; ++i) {
        a[i] += __shfl_xor(a[i], 8);
        a[i] += __shfl_xor(a[i], 16);
        a[i] += __shfl_xor(a[i], 32);
    }

    if (sub == 0) {
        float dd = dinv[d];
        float4* o4 = (float4*)out;
        o4[(size_t)d * 16 + 2 * q + 0] = make_float4(dd * a[0], dd * a[1], dd * a[2], dd * a[3]);
        o4[(size_t)d * 16 + 2 * q + 1] = make_float4(dd * a[4], dd * a[5], dd * a[6], dd * a[7]);
    }
}

// ============ centroid squared norms ============

__global__ void k_c2(const float* __restrict__ C, float* __restrict__ c2) {
    int k = threadIdx.x;
    if (k < 100) {
        float s = 0.f;
        for (int d = 0; d < 64; ++d) { float v = C[k * 64 + d]; s = fmaf(v, v, s); }
        c2[k] = s;
    }
}

// ============ centroid distances + pooling: thread = node, 4 k-groups ============
// grid = (node tiles) x 4; block handles 256 nodes x 25 centroids.

__global__ __launch_bounds__(256) void k_cent(const float* __restrict__ hin,
                                              const float* __restrict__ b2,
                                              const float* __restrict__ C,
                                              const float* __restrict__ c2g,
                                              float* __restrict__ pooled, int N) {
    __shared__ float pooled_s[32];
    int tid = threadIdx.x;
    int kg = blockIdx.y;                 // 0..3, covers k in [kg*25, kg*25+25)
    if (tid < 32) pooled_s[tid] = 0.f;
    __syncthreads();

    int n = blockIdx.x * 256 + tid;
    bool valid = n < N;

    float h[64];
    float h2 = 0.f;
    {
        const float4* h4 = (const float4*)(hin + ((size_t)(valid ? n : 0) << 6));
#pragma unroll
        for (int i = 0; i < 16; ++i) {
            float4 v = h4[i];
            v.x = fmaxf(v.x + b2[4 * i + 0], 0.f);
            v.y = fmaxf(v.y + b2[4 * i + 1], 0.f);
            v.z = fmaxf(v.z + b2[4 * i + 2], 0.f);
            v.w = fmaxf(v.w + b2[4 * i + 3], 0.f);
            h[4 * i + 0] = v.x; h[4 * i + 1] = v.y;
            h[4 * i + 2] = v.z; h[4 * i + 3] = v.w;
            h2 = fmaf(v.x, v.x, h2); h2 = fmaf(v.y, v.y, h2);
            h2 = fmaf(v.z, v.z, h2); h2 = fmaf(v.w, v.w, h2);
        }
    }

    int kbeg = kg * 25, kend = kbeg + 25;
    for (int k = kbeg; k < kend; ++k) {
        const float* crow = C + k * 64;   // wave-uniform -> scalar loads
        float acc = 0.f;
#pragma unroll
        for (int d = 0; d < 64; ++d) acc = fmaf(h[d], crow[d], acc);
        float d2 = fmaxf(h2 + c2g[k] - 2.f * acc, 0.f);
        float dist = valid ? sqrtf(d2 + 1e-12f) : 0.f;
#pragma unroll
        for (int off = 32; off > 0; off >>= 1) dist += __shfl_xor(dist, off);
        if ((tid & 63) == 0) atomicAdd(&pooled_s[k - kbeg], dist);
    }
    __syncthreads();
    if (tid < 25) atomicAdd(&pooled[kbeg + tid], pooled_s[tid]);
}

// ============ output head ============

__global__ void k_out(const float* __restrict__ pooled,
                      const float* __restrict__ Wout,
                      const float* __restrict__ bout,
                      float* __restrict__ out, float invN) {
    int t = threadIdx.x;
    if (t < 10) {
        float s = 0.f;
        for (int k = 0; k < 100; ++k) s += pooled[k] * Wout[t * 100 + k];
        out[t] = s * invN + bout[t];
    }
}

// ============ launcher ============

extern "C" void kernel_launch(void* const* d_in, const int* in_sizes, int n_in,
                              void* d_out, int out_size, void* d_ws, size_t ws_size,
                              hipStream_t stream) {
    const float* x    = (const float*)d_in[0];
    const int*   ei   = (const int*)d_in[1];
    const float* We   = (const float*)d_in[2];
    const float* Wg   = (const float*)d_in[3];
    const float* bg   = (const float*)d_in[4];
    const float* C    = (const float*)d_in[5];
    const float* Wout = (const float*)d_in[6];
    const float* bout = (const float*)d_in[7];
    float*       out  = (float*)d_out;

    const int N = in_sizes[0] / 128;          // 100000
    const int E = in_sizes[1] / 2;            // 1600000
    const int NBUCK = (N + 255) >> 8;         // 391 dst-buckets
    const int NCH = (E + CHUNK - 1) / CHUNK;  // 98 chunks
    const int NBN = (N + 255) / 256;

    char* ws = (char*)d_ws;
    size_t off = 0;
    auto alloc = [&](size_t bytes) { void* p = ws + off; off += (bytes + 511) & ~(size_t)511; return p; };
    float*  dinv   = (float*)alloc((size_t)N * 4);
    int*    counts = (int*)  alloc((size_t)N * 4);
    int*    rowptr = (int*)  alloc((size_t)N * 4);
    int*    bcnt   = (int*)  alloc((size_t)NBUCK * NCH * 4);
    int*    bofs   = (int*)  alloc((size_t)NBUCK * NCH * 4);
    int*    btot   = (int*)  alloc((size_t)NBUCK * 4);
    int*    bbase  = (int*)  alloc((size_t)(NBUCK + 1) * 4);
    uint32* ebuf   = (uint32*)alloc((size_t)E * 4);
    int*    ssrc   = (int*)  alloc((size_t)(E + 16) * 4);     // +16 pad for agg reads
    float*  hA     = (float*)alloc((size_t)N * 64 * 4);
    uint32* tab    = (uint32*)alloc((size_t)(N + 1) * 64);    // fp8 table + sentinel row
    float*  c2     = (float*)alloc(512);
    float*  pooled = (float*)alloc(512);

    hipMemsetAsync(pooled, 0, 512, stream);
    hipMemsetAsync(tab + (size_t)N * 16, 0, 64, stream);      // sentinel row N = 0

    // bucketed CSR build (no global atomics)
    k_bhist<<<NCH, 256, 0, stream>>>(ei + E, bcnt, E, NBUCK, NCH);
    k_bscan1<<<NBUCK, 128, 0, stream>>>(bcnt, bofs, btot, NCH);
    k_bscan2<<<1, 512, 0, stream>>>(btot, bbase, NBUCK);
    k_bscatter<<<NCH, 256, 0, stream>>>(ei, bbase, bofs, ebuf, E, NBUCK, NCH);
    k_bsort<<<NBUCK, 256, 0, stream>>>(ebuf, bbase, ssrc, rowptr, counts, dinv, N);
    k_c2<<<1, 128, 0, stream>>>(C, c2);

    // embed
    k_embed<<<N / 32, 256, 0, stream>>>(x, We, hA, N);

    // 3 GCN layers: gemm (hA -> fp8 tab, scaled by dinv), aggregate (tab -> hA fp32)
    for (int l = 0; l < 3; ++l) {
        const float* bias_prev = (l == 0) ? bg : (bg + (l - 1) * 64);
        int act = (l == 0) ? 0 : 1;
        k_gcn<<<N / 32, 256, 0, stream>>>(hA, Wg + (size_t)l * 64 * 64, bias_prev, act,
                                          dinv, tab, N);
        k_agg<<<(N + 3) / 4, 256, 0, stream>>>(rowptr, counts, ssrc, dinv,
                                               (const uint2*)tab, hA, N);
    }

    // centroid distances + pooling (applies relu + b_gcn[2]); 4 k-groups
    k_cent<<<dim3(NBN, 4), 256, 0, stream>>>(hA, bg + 2 * 64, C, c2, pooled, N);

    // head
    k_out<<<1, 64, 0, stream>>>(pooled, Wout, bout, out, 1.0f / (float)N);
}